// Round 7
// baseline (207.680 us; speedup 1.0000x reference)
//
#include <hip/hip_runtime.h>

#define N_SP 3136   // H*W
#define NP   3328   // padded N (104 x 32)
#define C_CH 256
#define CQ   32
#define NB   4
// 1 / (exp(sqrt(3))*sqrt(3136/256) + 2*sqrt(6))
#define INV_BOUND 0.04051569f
#define LOG2E 1.44269504f

typedef __attribute__((ext_vector_type(8))) short bf16x8;
typedef __attribute__((ext_vector_type(4))) float f32x4;
typedef __attribute__((ext_vector_type(2))) unsigned int u32x2;
typedef unsigned short u16;
typedef unsigned int   u32;

#define MFMA16(a,b,c) __builtin_amdgcn_mfma_f32_16x16x32_bf16(a,b,c,0,0,0)

__device__ __forceinline__ u16 f2b(float f) {
    u32 u = __builtin_bit_cast(u32, f);
    u += 0x7fffu + ((u >> 16) & 1u);   // RTNE
    return (u16)(u >> 16);
}
__device__ __forceinline__ u32 pk_bf16(float a, float b) {
    return (u32)f2b(a) | ((u32)f2b(b) << 16);
}

// ---------------------------------------------------------------------------
// stage1: fused xT transpose (blocks 0..783), W->bf16 (784..863), norm (864)
// ---------------------------------------------------------------------------
__global__ __launch_bounds__(256) void stage1_kernel(
    const float* __restrict__ x, const float* __restrict__ Wq,
    const float* __restrict__ Wk, const float* __restrict__ Wv,
    u16* __restrict__ xT, u16* __restrict__ Wqb, u16* __restrict__ Wkb,
    u16* __restrict__ Wvb, float* __restrict__ scale_out)
{
    __shared__ float smem[64 * 65];
    const int t = threadIdx.x;
    const int bid = blockIdx.x;

    if (bid < 784) {                       // xT[b][n][c] = bf16(x[b][c][n])
        float (*tile)[65] = (float(*)[65])smem;
        const int ct = bid & 3, nt = (bid >> 2) % 49, b = bid / 196;
        const int c0 = ct * 64, n0 = nt * 64;
        const int cc = t >> 4, nn4 = (t & 15) * 4;
        #pragma unroll
        for (int i = 0; i < 4; ++i) {
            int cl = cc + i * 16;
            float4 v = *(const float4*)(x + (size_t)(b * C_CH + c0 + cl) * N_SP + n0 + nn4);
            tile[cl][nn4] = v.x; tile[cl][nn4 + 1] = v.y;
            tile[cl][nn4 + 2] = v.z; tile[cl][nn4 + 3] = v.w;
        }
        __syncthreads();
        const int c4 = (t & 15) * 4, nn = t >> 4;
        #pragma unroll
        for (int i = 0; i < 4; ++i) {
            int nl = nn + i * 16;
            ushort4 o;
            o.x = f2b(tile[c4 + 0][nl]); o.y = f2b(tile[c4 + 1][nl]);
            o.z = f2b(tile[c4 + 2][nl]); o.w = f2b(tile[c4 + 3][nl]);
            *(ushort4*)(xT + (size_t)(b * N_SP + n0 + nl) * C_CH + c0 + c4) = o;
        }
    } else if (bid < 864) {                // W f32 -> bf16
        int idx = (bid - 784) * 256 + t;
        const float* src; u16* dst; int off;
        if (idx < 2048)      { src = Wq; dst = Wqb; off = idx; }
        else if (idx < 4096) { src = Wk; dst = Wkb; off = idx - 2048; }
        else                 { src = Wv; dst = Wvb; off = idx - 4096; }
        float4 v = *(const float4*)(src + off * 4);
        ushort4 o; o.x = f2b(v.x); o.y = f2b(v.y); o.z = f2b(v.z); o.w = f2b(v.w);
        *(ushort4*)(dst + off * 4) = o;
    } else {                               // norm -> scale
        float* red = smem;
        float u2 = 0.f;
        for (int i = t; i < CQ * C_CH; i += 256) { float w = Wq[i]; u2 += w * w; }
        red[t] = u2; __syncthreads();
        #pragma unroll
        for (int s = 128; s > 0; s >>= 1) { if (t < s) red[t] += red[t + s]; __syncthreads(); }
        float u2t = red[0]; __syncthreads();
        float vn2 = 0.f;
        for (int o = 0; o < CQ; ++o)   { float w = Wk[o * C_CH + t]; vn2 += w * w; }
        float wn2 = 0.f;
        for (int o = 0; o < C_CH; ++o) { float w = Wv[o * C_CH + t]; wn2 += w * w; }
        red[t] = fmaxf(vn2, wn2); __syncthreads();
        #pragma unroll
        for (int s = 128; s > 0; s >>= 1) { if (t < s) red[t] = fmaxf(red[t], red[t + s]); __syncthreads(); }
        if (t == 0) scale_out[0] = 1.0f / (sqrtf(u2t) * sqrtf(red[0]));
    }
}

// ---------------------------------------------------------------------------
// qkv via MFMA, 5-way row split (split0: q+k, split1..4: 64 V-rows each).
// kT/Vb use padded stride NP; blocks 980..983 zero the pad region [3136,3328).
// qT pre-multiplied by scale*log2(e); emits qnorm[b][n], kmax[b] (atomicMax).
// ---------------------------------------------------------------------------
__global__ __launch_bounds__(256) void qkv_mfma(
    const u16* __restrict__ xT, const u16* __restrict__ Wqb,
    const u16* __restrict__ Wkb, const u16* __restrict__ Wvb,
    const float* __restrict__ bq, const float* __restrict__ bk,
    const float* __restrict__ bv, const float* __restrict__ scale_p,
    u16* __restrict__ qT, u16* __restrict__ kT, u16* __restrict__ Vb,
    float* __restrict__ qnorm, float* __restrict__ kmax)
{
    const int t = threadIdx.x;

    if (blockIdx.x >= 980) {               // zero j-pad [3136, 3328)
        const int b = blockIdx.x - 980;
        uint4 z = make_uint4(0u, 0u, 0u, 0u);
        if (t < 192) {                     // kT: 192 pad rows x 32 ck
            u16* krow = kT + ((size_t)b * NP + 3136 + t) * CQ;
            #pragma unroll
            for (int i = 0; i < 4; ++i) *(uint4*)(krow + i * 8) = z;
        }
        u16* vrow = Vb + ((size_t)b * C_CH + t) * NP + 3136;   // c = t, 192 elems
        #pragma unroll
        for (int i = 0; i < 24; ++i) *(uint4*)(vrow + i * 8) = z;
        return;
    }

    const int split = blockIdx.x / 196, tile = blockIdx.x % 196;
    const int b = tile / 49, nt = tile % 49;
    const int w = t >> 6, li = t & 15, g = (t >> 4) & 3;
    const int n = nt * 64 + w * 16 + li;
    const f32x4 zero = {0.f, 0.f, 0.f, 0.f};

    bf16x8 xf[8];
    #pragma unroll
    for (int ks = 0; ks < 8; ++ks)
        xf[ks] = *(const bf16x8*)(xT + (size_t)(b * N_SP + n) * C_CH + ks * 32 + 8 * g);

    if (split == 0) {
        f32x4 aq0 = zero, aq1 = zero, ak0 = zero, ak1 = zero;
        #pragma unroll
        for (int ks = 0; ks < 8; ++ks) {
            bf16x8 w0 = *(const bf16x8*)(Wqb + li * C_CH + ks * 32 + 8 * g);
            bf16x8 w1 = *(const bf16x8*)(Wqb + (16 + li) * C_CH + ks * 32 + 8 * g);
            bf16x8 w2 = *(const bf16x8*)(Wkb + li * C_CH + ks * 32 + 8 * g);
            bf16x8 w3 = *(const bf16x8*)(Wkb + (16 + li) * C_CH + ks * 32 + 8 * g);
            aq0 = MFMA16(w0, xf[ks], aq0);
            aq1 = MFMA16(w1, xf[ks], aq1);
            ak0 = MFMA16(w2, xf[ks], ak0);
            ak1 = MFMA16(w3, xf[ks], ak1);
        }
        const float scf = scale_p[0] * LOG2E;
        f32x4 bq0 = *(const f32x4*)(bq + 4 * g);
        f32x4 bq1 = *(const f32x4*)(bq + 16 + 4 * g);
        f32x4 bk0 = *(const f32x4*)(bk + 4 * g);
        f32x4 bk1 = *(const f32x4*)(bk + 16 + 4 * g);
        float qn2 = 0.f, kn2 = 0.f;
        ushort4 s0, s1;
        #pragma unroll
        for (int r = 0; r < 4; ++r) {
            float q0 = (aq0[r] + bq0[r]) * scf;
            float q1 = (aq1[r] + bq1[r]) * scf;
            qn2 += q0 * q0 + q1 * q1;
            ((u16*)&s0)[r] = f2b(q0); ((u16*)&s1)[r] = f2b(q1);
        }
        *(ushort4*)(qT + (size_t)(b * N_SP + n) * CQ + 4 * g)      = s0;
        *(ushort4*)(qT + (size_t)(b * N_SP + n) * CQ + 16 + 4 * g) = s1;
        #pragma unroll
        for (int r = 0; r < 4; ++r) {
            float k0 = ak0[r] + bk0[r];
            float k1 = ak1[r] + bk1[r];
            kn2 += k0 * k0 + k1 * k1;
            ((u16*)&s0)[r] = f2b(k0); ((u16*)&s1)[r] = f2b(k1);
        }
        *(ushort4*)(kT + (size_t)(b * NP + n) * CQ + 4 * g)      = s0;
        *(ushort4*)(kT + (size_t)(b * NP + n) * CQ + 16 + 4 * g) = s1;

        qn2 += __shfl_xor(qn2, 16); qn2 += __shfl_xor(qn2, 32);
        kn2 += __shfl_xor(kn2, 16); kn2 += __shfl_xor(kn2, 32);
        if (g == 0) qnorm[b * N_SP + n] = sqrtf(qn2);
        float kn = sqrtf(kn2);
        #pragma unroll
        for (int d = 1; d < 16; d <<= 1) kn = fmaxf(kn, __shfl_xor(kn, d));
        if ((t & 63) == 0) atomicMax((int*)(kmax + b), __float_as_int(kn));
    } else {
        const int r0 = (split - 1) * 64;
        f32x4 a[4] = {zero, zero, zero, zero};
        #pragma unroll
        for (int ks = 0; ks < 8; ++ks) {
            #pragma unroll
            for (int fr = 0; fr < 4; ++fr) {
                bf16x8 wf = *(const bf16x8*)(Wvb + (size_t)(r0 + fr * 16 + li) * C_CH + ks * 32 + 8 * g);
                a[fr] = MFMA16(wf, xf[ks], a[fr]);
            }
        }
        #pragma unroll
        for (int fr = 0; fr < 4; ++fr) {
            f32x4 bb = *(const f32x4*)(bv + r0 + fr * 16 + 4 * g);
            #pragma unroll
            for (int r = 0; r < 4; ++r)
                Vb[(size_t)(b * C_CH + r0 + fr * 16 + 4 * g + r) * NP + n] = f2b(a[fr][r] + bb[r]);
        }
    }
}

// ---------------------------------------------------------------------------
// Attention: 392 blocks x 512 thr (8 waves), BARRIER-FREE main loop.
// Block = 32 q x 256 ch; wave w owns j-chunks {w, w+8, ...} (13 x 32j).
// Per chunk: K-frags -> 4 S^T MFMA -> exp2 -> private swizzled LDS P (2KB,
// same-wave ds, no barrier) -> 2 A-frags -> 16 V-frags -> 32 PV MFMA into
// acc[2][16]. C-S bound exponent is j-independent => partials sum exactly;
// 7-barrier LDS tree-reduce at the end + pad correction (192 zero-k cols).
// ---------------------------------------------------------------------------
__global__ __launch_bounds__(512, 2) void attn_mfma(
    const u16* __restrict__ qT, const u16* __restrict__ kT,
    const u16* __restrict__ Vb, const float* __restrict__ x,
    const float* __restrict__ gamma_p, const float* __restrict__ qnorm,
    const float* __restrict__ kmax, float* __restrict__ out)
{
    __shared__ __align__(16) unsigned char Pw[8][2048];   // per-wave P, 16 KB
    __shared__ __align__(16) float rbuf[2][8192];         // reduce ping-pong, 64 KB
    __shared__ float red[8][32];
    __shared__ __align__(16) float red_final[32];

    const int t = threadIdx.x;
    const int w = t >> 6, li = t & 15, g = (t >> 4) & 3;
    const int sw = (li & 3) << 4;                         // P swizzle (64B rows)

    const int xcd = blockIdx.x & 7, idx = blockIdx.x >> 3;   // 392 = 8*49
    const int b  = xcd >> 1;
    const int i0 = ((xcd & 1) * 49 + idx) * 32;

    const u16* qTb = qT + (size_t)b * N_SP * CQ;
    const u16* kTb = kT + (size_t)b * NP * CQ;
    const u16* Vbb = Vb + (size_t)b * C_CH * NP;
    const float kmb = kmax[b];
    const f32x4 zero = {0.f, 0.f, 0.f, 0.f};

    const bf16x8 qf0 = *(const bf16x8*)(qTb + (size_t)(i0 + li) * CQ + 8 * g);
    const bf16x8 qf1 = *(const bf16x8*)(qTb + (size_t)(i0 + 16 + li) * CQ + 8 * g);
    const float mr0 = qnorm[b * N_SP + i0 + li] * kmb;
    const float mr1 = qnorm[b * N_SP + i0 + 16 + li] * kmb;

    unsigned char* P = Pw[w];
    const int wrRow0 = li * 64, wrRow1 = (16 + li) * 64;

    f32x4 acc[2][16];
    #pragma unroll
    for (int qi = 0; qi < 2; ++qi)
        #pragma unroll
        for (int cf = 0; cf < 16; ++cf) acc[qi][cf] = zero;
    float ls0 = 0.f, ls1 = 0.f;

    // prefetch K-frags for chunk 0
    int jc0 = w * 32;
    bf16x8 kfA = *(const bf16x8*)(kTb + (size_t)(jc0 + li) * CQ + 8 * g);
    bf16x8 kfB = *(const bf16x8*)(kTb + (size_t)(jc0 + 16 + li) * CQ + 8 * g);

    #pragma unroll 1
    for (int s = 0; s < 13; ++s) {
        const int jc = (w + s * 8) * 32;
        const int jn = (s == 12) ? jc : jc + 256;
        // issue all 16 V-frag loads for this chunk early
        bf16x8 vf[16];
        #pragma unroll
        for (int cf = 0; cf < 16; ++cf)
            vf[cf] = *(const bf16x8*)(Vbb + (size_t)(cf * 16 + li) * NP + jc + 8 * g);
        // S^T for both q-frags
        f32x4 sA0 = MFMA16(kfA, qf0, zero);
        f32x4 sA1 = MFMA16(kfA, qf1, zero);
        f32x4 sB0 = MFMA16(kfB, qf0, zero);
        f32x4 sB1 = MFMA16(kfB, qf1, zero);
        // prefetch next chunk's K-frags
        kfA = *(const bf16x8*)(kTb + (size_t)(jn + li) * CQ + 8 * g);
        kfB = *(const bf16x8*)(kTb + (size_t)(jn + 16 + li) * CQ + 8 * g);
        // softmax numerators
        float pA00 = exp2f(sA0[0] - mr0), pA01 = exp2f(sA0[1] - mr0);
        float pA02 = exp2f(sA0[2] - mr0), pA03 = exp2f(sA0[3] - mr0);
        float pA10 = exp2f(sA1[0] - mr1), pA11 = exp2f(sA1[1] - mr1);
        float pA12 = exp2f(sA1[2] - mr1), pA13 = exp2f(sA1[3] - mr1);
        float pB00 = exp2f(sB0[0] - mr0), pB01 = exp2f(sB0[1] - mr0);
        float pB02 = exp2f(sB0[2] - mr0), pB03 = exp2f(sB0[3] - mr0);
        float pB10 = exp2f(sB1[0] - mr1), pB11 = exp2f(sB1[1] - mr1);
        float pB12 = exp2f(sB1[2] - mr1), pB13 = exp2f(sB1[3] - mr1);
        ls0 += ((pA00 + pA01) + (pA02 + pA03)) + ((pB00 + pB01) + (pB02 + pB03));
        ls1 += ((pA10 + pA11) + (pA12 + pA13)) + ((pB10 + pB11) + (pB12 + pB13));
        // transpose-write P (private, swizzled), then A-frag reads (same wave)
        u32x2 wv;
        wv.x = pk_bf16(pA00, pA01); wv.y = pk_bf16(pA02, pA03);
        *(u32x2*)(P + wrRow0 + ((8 * g) ^ sw)) = wv;
        wv.x = pk_bf16(pB00, pB01); wv.y = pk_bf16(pB02, pB03);
        *(u32x2*)(P + wrRow0 + ((32 + 8 * g) ^ sw)) = wv;
        wv.x = pk_bf16(pA10, pA11); wv.y = pk_bf16(pA12, pA13);
        *(u32x2*)(P + wrRow1 + ((8 * g) ^ sw)) = wv;
        wv.x = pk_bf16(pB10, pB11); wv.y = pk_bf16(pB12, pB13);
        *(u32x2*)(P + wrRow1 + ((32 + 8 * g) ^ sw)) = wv;
        bf16x8 pa0 = *(const bf16x8*)(P + wrRow0 + ((16 * g) ^ sw));
        bf16x8 pa1 = *(const bf16x8*)(P + wrRow1 + ((16 * g) ^ sw));
        // PV
        __builtin_amdgcn_s_setprio(1);
        #pragma unroll
        for (int cf = 0; cf < 16; ++cf) {
            acc[0][cf] = MFMA16(pa0, vf[cf], acc[0][cf]);
            acc[1][cf] = MFMA16(pa1, vf[cf], acc[1][cf]);
        }
        __builtin_amdgcn_s_setprio(0);
    }

    // ---- denominator partials ----
    ls0 += __shfl_xor(ls0, 16); ls0 += __shfl_xor(ls0, 32);
    ls1 += __shfl_xor(ls1, 16); ls1 += __shfl_xor(ls1, 32);
    if ((t & 63) < 16) { red[w][li] = ls0; red[w][16 + li] = ls1; }

    // ---- acc tree-reduce through rbuf (8 -> 4 -> 2 -> 1) ----
    const int swr = (li & 7) << 4;   // 128B-row swizzle
#define RB(buf, cf, qi) ((f32x4*)((unsigned char*)(buf) + ((cf) * 16 + li) * 128 + (((qi) * 64 + 16 * g) ^ swr)))
#define RB_STORE(buf) { _Pragma("unroll") for (int qi = 0; qi < 2; ++qi) _Pragma("unroll") for (int cf = 0; cf < 16; ++cf) *RB(buf, cf, qi) = acc[qi][cf]; }
#define RB_ADD(buf)   { _Pragma("unroll") for (int qi = 0; qi < 2; ++qi) _Pragma("unroll") for (int cf = 0; cf < 16; ++cf) { f32x4 v_ = *RB(buf, cf, qi); _Pragma("unroll") for (int r = 0; r < 4; ++r) acc[qi][cf][r] += v_[r]; } }

    if (w == 4) RB_STORE(rbuf[0]); if (w == 5) RB_STORE(rbuf[1]);
    __syncthreads();
    if (w == 0) RB_ADD(rbuf[0]);   if (w == 1) RB_ADD(rbuf[1]);
    if (t < 32) {   // finalize denominators (+ pad correction)
        float sv = 0.f;
        #pragma unroll
        for (int ww = 0; ww < 8; ++ww) sv += red[ww][t];
        red_final[t] = sv - 192.0f * exp2f(-qnorm[b * N_SP + i0 + t] * kmb);
    }
    __syncthreads();
    if (w == 6) RB_STORE(rbuf[0]); if (w == 7) RB_STORE(rbuf[1]);
    __syncthreads();
    if (w == 2) RB_ADD(rbuf[0]);   if (w == 3) RB_ADD(rbuf[1]);
    __syncthreads();
    if (w == 2) RB_STORE(rbuf[0]); if (w == 3) RB_STORE(rbuf[1]);
    __syncthreads();
    if (w == 0) RB_ADD(rbuf[0]);   if (w == 1) RB_ADD(rbuf[1]);
    __syncthreads();
    if (w == 1) RB_STORE(rbuf[0]);
    __syncthreads();

    if (w == 0) {
        RB_ADD(rbuf[0]);
        const float gsc = gamma_p[0] * INV_BOUND;
        #pragma unroll
        for (int qi = 0; qi < 2; ++qi) {
            f32x4 lsv = *(const f32x4*)(red_final + qi * 16 + 4 * g);
            f32x4 rinv;
            #pragma unroll
            for (int r = 0; r < 4; ++r) rinv[r] = gsc / lsv[r];
            #pragma unroll
            for (int cf = 0; cf < 16; ++cf) {
                const int c = cf * 16 + li;
                const size_t base = ((size_t)b * C_CH + c) * N_SP + i0 + qi * 16 + 4 * g;
                float4 xv = *(const float4*)(x + base);
                float4 o;
                o.x = acc[qi][cf][0] * rinv[0] + xv.x;
                o.y = acc[qi][cf][1] * rinv[1] + xv.y;
                o.z = acc[qi][cf][2] * rinv[2] + xv.z;
                o.w = acc[qi][cf][3] * rinv[3] + xv.w;
                *(float4*)(out + base) = o;
            }
        }
    }
#undef RB
#undef RB_STORE
#undef RB_ADD
}

// ---------------------------------------------------------------------------
extern "C" void kernel_launch(void* const* d_in, const int* in_sizes, int n_in,
                              void* d_out, int out_size, void* d_ws, size_t ws_size,
                              hipStream_t stream)
{
    const float* x  = (const float*)d_in[0];
    const float* Wq = (const float*)d_in[1];
    const float* bq = (const float*)d_in[2];
    const float* Wk = (const float*)d_in[3];
    const float* bk = (const float*)d_in[4];
    const float* Wv = (const float*)d_in[5];
    const float* bv = (const float*)d_in[6];
    const float* gm = (const float*)d_in[7];
    float* out = (float*)d_out;
    float* ws  = (float*)d_ws;

    float* scale = ws;                       // [0..3]
    float* kmax  = ws + 4;                   // [4..7], per-batch
    float* qnorm = ws + 8;                   // NB*N_SP floats
    u16* Wqb = (u16*)(ws + 8 + NB * N_SP);   // 16B-aligned (50208 % 16 == 0)
    u16* Wkb = Wqb + 32 * 256;
    u16* Wvb = Wkb + 32 * 256;
    u16* xT  = Wvb + 256 * 256;
    u16* qT  = xT + (size_t)NB * N_SP * C_CH;
    u16* kT  = qT + (size_t)NB * N_SP * CQ;
    u16* Vb  = kT + (size_t)NB * NP * CQ;

    (void)hipMemsetAsync(kmax, 0, NB * sizeof(float), stream);
    stage1_kernel<<<865, 256, 0, stream>>>(x, Wq, Wk, Wv, xT, Wqb, Wkb, Wvb, scale);
    qkv_mfma<<<984, 256, 0, stream>>>(xT, Wqb, Wkb, Wvb, bq, bk, bv, scale, qT, kT, Vb, qnorm, kmax);
    attn_mfma<<<392, 512, 0, stream>>>(qT, kT, Vb, x, gm, qnorm, kmax, out);
}

// Round 8
// 162.776 us; speedup vs baseline: 1.2759x; 1.2759x over previous
//
#include <hip/hip_runtime.h>

#define N_SP 3136   // H*W
#define NP   3200   // padded N (25 x 128)
#define NT   25     // attn j-tiles of 128
#define C_CH 256
#define CQ   32
#define NB   4
// 1 / (exp(sqrt(3))*sqrt(3136/256) + 2*sqrt(6))
#define INV_BOUND 0.04051569f
#define LOG2E 1.44269504f

typedef __attribute__((ext_vector_type(8))) short bf16x8;
typedef __attribute__((ext_vector_type(4))) float f32x4;
typedef __attribute__((ext_vector_type(2))) unsigned int u32x2;
typedef unsigned short u16;
typedef unsigned int   u32;

#define MFMA16(a,b,c) __builtin_amdgcn_mfma_f32_16x16x32_bf16(a,b,c,0,0,0)

__device__ __forceinline__ u16 f2b(float f) {
    u32 u = __builtin_bit_cast(u32, f);
    u += 0x7fffu + ((u >> 16) & 1u);   // RTNE
    return (u16)(u >> 16);
}
__device__ __forceinline__ u32 pk_bf16(float a, float b) {
    return (u32)f2b(a) | ((u32)f2b(b) << 16);
}

// ---------------------------------------------------------------------------
// stage1: xT transpose (blocks 0..783, XCD-affine: batch b -> XCD {2b,2b+1}),
// W->bf16 (784..863), norm (864).
// ---------------------------------------------------------------------------
__global__ __launch_bounds__(256) void stage1_kernel(
    const float* __restrict__ x, const float* __restrict__ Wq,
    const float* __restrict__ Wk, const float* __restrict__ Wv,
    u16* __restrict__ xT, u16* __restrict__ Wqb, u16* __restrict__ Wkb,
    u16* __restrict__ Wvb, float* __restrict__ scale_out)
{
    __shared__ float smem[64 * 65];
    const int t = threadIdx.x;
    const int bid = blockIdx.x;

    if (bid < 784) {                       // xT[b][n][c] = bf16(x[b][c][n])
        float (*tile)[65] = (float(*)[65])smem;
        // XCD-affine decode: 784 = 98 slots x 8 XCDs; batch b on XCDs 2b,2b+1
        const int xcd = bid & 7, slot = bid >> 3;
        const int b = xcd >> 1;
        const int i = slot * 2 + (xcd & 1);          // 0..195
        const int ct = i & 3, nt = i >> 2;           // 4 x 49
        const int c0 = ct * 64, n0 = nt * 64;
        const int cc = t >> 4, nn4 = (t & 15) * 4;
        #pragma unroll
        for (int k = 0; k < 4; ++k) {
            int cl = cc + k * 16;
            float4 v = *(const float4*)(x + (size_t)(b * C_CH + c0 + cl) * N_SP + n0 + nn4);
            tile[cl][nn4] = v.x; tile[cl][nn4 + 1] = v.y;
            tile[cl][nn4 + 2] = v.z; tile[cl][nn4 + 3] = v.w;
        }
        __syncthreads();
        const int c4 = (t & 15) * 4, nn = t >> 4;
        #pragma unroll
        for (int k = 0; k < 4; ++k) {
            int nl = nn + k * 16;
            ushort4 o;
            o.x = f2b(tile[c4 + 0][nl]); o.y = f2b(tile[c4 + 1][nl]);
            o.z = f2b(tile[c4 + 2][nl]); o.w = f2b(tile[c4 + 3][nl]);
            *(ushort4*)(xT + (size_t)(b * N_SP + n0 + nl) * C_CH + c0 + c4) = o;
        }
    } else if (bid < 864) {                // W f32 -> bf16
        int idx = (bid - 784) * 256 + t;
        const float* src; u16* dst; int off;
        if (idx < 2048)      { src = Wq; dst = Wqb; off = idx; }
        else if (idx < 4096) { src = Wk; dst = Wkb; off = idx - 2048; }
        else                 { src = Wv; dst = Wvb; off = idx - 4096; }
        float4 v = *(const float4*)(src + off * 4);
        ushort4 o; o.x = f2b(v.x); o.y = f2b(v.y); o.z = f2b(v.z); o.w = f2b(v.w);
        *(ushort4*)(dst + off * 4) = o;
    } else {                               // norm -> scale
        float* red = smem;
        float u2 = 0.f;
        for (int i = t; i < CQ * C_CH; i += 256) { float w = Wq[i]; u2 += w * w; }
        red[t] = u2; __syncthreads();
        #pragma unroll
        for (int s = 128; s > 0; s >>= 1) { if (t < s) red[t] += red[t + s]; __syncthreads(); }
        float u2t = red[0]; __syncthreads();
        float vn2 = 0.f;
        for (int o = 0; o < CQ; ++o)   { float w = Wk[o * C_CH + t]; vn2 += w * w; }
        float wn2 = 0.f;
        for (int o = 0; o < C_CH; ++o) { float w = Wv[o * C_CH + t]; wn2 += w * w; }
        red[t] = fmaxf(vn2, wn2); __syncthreads();
        #pragma unroll
        for (int s = 128; s > 0; s >>= 1) { if (t < s) red[t] = fmaxf(red[t], red[t + s]); __syncthreads(); }
        if (t == 0) scale_out[0] = 1.0f / (sqrtf(u2t) * sqrtf(red[0]));
    }
}

// ---------------------------------------------------------------------------
// qkv via MFMA, XCD-affine grid: 984 = 123 slots x 8 XCDs; batch b = xcd>>1,
// i = slot*2 + (xcd&1) in [0,246): i==245 -> pad-zero block, else
// split = i/49 (0: q+k, 1..4: 64 V-rows), nt = i%49.
// kT/Vb use padded stride NP. qT pre-multiplied by scale*log2(e);
// emits qnorm[b][n], kmax[b] (atomicMax).
// ---------------------------------------------------------------------------
__global__ __launch_bounds__(256) void qkv_mfma(
    const u16* __restrict__ xT, const u16* __restrict__ Wqb,
    const u16* __restrict__ Wkb, const u16* __restrict__ Wvb,
    const float* __restrict__ bq, const float* __restrict__ bk,
    const float* __restrict__ bv, const float* __restrict__ scale_p,
    u16* __restrict__ qT, u16* __restrict__ kT, u16* __restrict__ Vb,
    float* __restrict__ qnorm, float* __restrict__ kmax)
{
    const int t = threadIdx.x;
    const int xcd = blockIdx.x & 7, slot = blockIdx.x >> 3;
    const int b = xcd >> 1;
    const int i = slot * 2 + (xcd & 1);

    if (i >= 245) {                        // zero j-pad [3136, 3200) for batch b
        uint4 z = make_uint4(0u, 0u, 0u, 0u);
        *(uint4*)(kT + ((size_t)b * NP + 3136) * CQ + t * 8) = z;   // 64 rows x 32
        u16* vrow = Vb + ((size_t)b * C_CH + t) * NP + 3136;        // c = t, 64 elems
        #pragma unroll
        for (int k = 0; k < 8; ++k) *(uint4*)(vrow + k * 8) = z;
        return;
    }

    const int split = i / 49, nt = i % 49;
    const int w = t >> 6, li = t & 15, g = (t >> 4) & 3;
    const int n = nt * 64 + w * 16 + li;
    const f32x4 zero = {0.f, 0.f, 0.f, 0.f};

    bf16x8 xf[8];
    #pragma unroll
    for (int ks = 0; ks < 8; ++ks)
        xf[ks] = *(const bf16x8*)(xT + (size_t)(b * N_SP + n) * C_CH + ks * 32 + 8 * g);

    if (split == 0) {
        f32x4 aq0 = zero, aq1 = zero, ak0 = zero, ak1 = zero;
        #pragma unroll
        for (int ks = 0; ks < 8; ++ks) {
            bf16x8 w0 = *(const bf16x8*)(Wqb + li * C_CH + ks * 32 + 8 * g);
            bf16x8 w1 = *(const bf16x8*)(Wqb + (16 + li) * C_CH + ks * 32 + 8 * g);
            bf16x8 w2 = *(const bf16x8*)(Wkb + li * C_CH + ks * 32 + 8 * g);
            bf16x8 w3 = *(const bf16x8*)(Wkb + (16 + li) * C_CH + ks * 32 + 8 * g);
            aq0 = MFMA16(w0, xf[ks], aq0);
            aq1 = MFMA16(w1, xf[ks], aq1);
            ak0 = MFMA16(w2, xf[ks], ak0);
            ak1 = MFMA16(w3, xf[ks], ak1);
        }
        const float scf = scale_p[0] * LOG2E;
        f32x4 bq0 = *(const f32x4*)(bq + 4 * g);
        f32x4 bq1 = *(const f32x4*)(bq + 16 + 4 * g);
        f32x4 bk0 = *(const f32x4*)(bk + 4 * g);
        f32x4 bk1 = *(const f32x4*)(bk + 16 + 4 * g);
        float qn2 = 0.f, kn2 = 0.f;
        ushort4 s0, s1;
        #pragma unroll
        for (int r = 0; r < 4; ++r) {
            float q0 = (aq0[r] + bq0[r]) * scf;
            float q1 = (aq1[r] + bq1[r]) * scf;
            qn2 += q0 * q0 + q1 * q1;
            ((u16*)&s0)[r] = f2b(q0); ((u16*)&s1)[r] = f2b(q1);
        }
        *(ushort4*)(qT + (size_t)(b * N_SP + n) * CQ + 4 * g)      = s0;
        *(ushort4*)(qT + (size_t)(b * N_SP + n) * CQ + 16 + 4 * g) = s1;
        #pragma unroll
        for (int r = 0; r < 4; ++r) {
            float k0 = ak0[r] + bk0[r];
            float k1 = ak1[r] + bk1[r];
            kn2 += k0 * k0 + k1 * k1;
            ((u16*)&s0)[r] = f2b(k0); ((u16*)&s1)[r] = f2b(k1);
        }
        *(ushort4*)(kT + (size_t)(b * NP + n) * CQ + 4 * g)      = s0;
        *(ushort4*)(kT + (size_t)(b * NP + n) * CQ + 16 + 4 * g) = s1;

        qn2 += __shfl_xor(qn2, 16); qn2 += __shfl_xor(qn2, 32);
        kn2 += __shfl_xor(kn2, 16); kn2 += __shfl_xor(kn2, 32);
        if (g == 0) qnorm[b * N_SP + n] = sqrtf(qn2);
        float kn = sqrtf(kn2);
        #pragma unroll
        for (int d = 1; d < 16; d <<= 1) kn = fmaxf(kn, __shfl_xor(kn, d));
        if ((t & 63) == 0) atomicMax((int*)(kmax + b), __float_as_int(kn));
    } else {
        const int r0 = (split - 1) * 64;
        f32x4 a[4] = {zero, zero, zero, zero};
        #pragma unroll
        for (int ks = 0; ks < 8; ++ks) {
            #pragma unroll
            for (int fr = 0; fr < 4; ++fr) {
                bf16x8 wf = *(const bf16x8*)(Wvb + (size_t)(r0 + fr * 16 + li) * C_CH + ks * 32 + 8 * g);
                a[fr] = MFMA16(wf, xf[ks], a[fr]);
            }
        }
        #pragma unroll
        for (int fr = 0; fr < 4; ++fr) {
            f32x4 bb = *(const f32x4*)(bv + r0 + fr * 16 + 4 * g);
            #pragma unroll
            for (int r = 0; r < 4; ++r)
                Vb[(size_t)(b * C_CH + r0 + fr * 16 + 4 * g + r) * NP + n] = f2b(a[fr][r] + bb[r]);
        }
    }
}

// ---------------------------------------------------------------------------
// Attention (R6 body, verified): 392 blocks x 512 thr (8 waves), 128-j tiles.
// Batch b pinned to XCDs {2b, 2b+1} -- now matching where qkv wrote K/V/q.
// ---------------------------------------------------------------------------
__global__ __launch_bounds__(512, 4) void attn_mfma(
    const u16* __restrict__ qT, const u16* __restrict__ kT,
    const u16* __restrict__ Vb, const float* __restrict__ x,
    const float* __restrict__ gamma_p, const float* __restrict__ qnorm,
    const float* __restrict__ kmax, float* __restrict__ out)
{
    __shared__ __align__(16) unsigned char P[2][32 * 256];   // 16 KB, swizzled
    __shared__ float red[8][16];
    __shared__ __align__(16) float red_final[32];

    const int t = threadIdx.x;
    const int w = t >> 6, li = t & 15, g = (t >> 4) & 3;
    const int qf = w >> 2, jh = w & 3;
    const int f0 = 2 * jh, f1 = f0 + 1;      // this wave's 16-j frags in tile
    const int cw = w * 32;                   // PV channel base
    const int sw = (li & 7) << 4;            // XOR swizzle

    const int xcd = blockIdx.x & 7, idx = blockIdx.x >> 3;   // 392 = 8*49
    const int b  = xcd >> 1;
    const int i0 = ((xcd & 1) * 49 + idx) * 32;

    const u16* qTb = qT + (size_t)b * N_SP * CQ;
    const u16* kTb = kT + (size_t)b * NP * CQ;
    const u16* Vbb = Vb + ((size_t)b * C_CH + cw) * NP;
    const float kmb = kmax[b];
    const f32x4 zero = {0.f, 0.f, 0.f, 0.f};

    const bf16x8 qfS = *(const bf16x8*)(qTb + (size_t)(i0 + qf * 16 + li) * CQ + 8 * g);
    const float  mrS = qnorm[b * N_SP + i0 + qf * 16 + li] * kmb;

    const int pwOff0 = (qf * 16 + li) * 256 + ((f0 * 32 + 8 * g) ^ sw);
    const int pwOff1 = (qf * 16 + li) * 256 + ((f1 * 32 + 8 * g) ^ sw);
    const int prRow0 = li * 256, prRow1 = (16 + li) * 256;

    f32x4 acc[2][2];
    acc[0][0] = zero; acc[0][1] = zero; acc[1][0] = zero; acc[1][1] = zero;
    float ls = 0.f;

    // prefetch tile 0 (K rows + V frags)
    bf16x8 kf0 = *(const bf16x8*)(kTb + (size_t)(f0 * 16 + li) * CQ + 8 * g);
    bf16x8 kf1 = *(const bf16x8*)(kTb + (size_t)(f1 * 16 + li) * CQ + 8 * g);
    bf16x8 vf[2][4];
    #pragma unroll
    for (int cf = 0; cf < 2; ++cf)
        #pragma unroll
        for (int ks = 0; ks < 4; ++ks)
            vf[cf][ks] = *(const bf16x8*)(Vbb + (size_t)(cf * 16 + li) * NP + ks * 32 + 8 * g);

    #pragma unroll 2
    for (int it = 0; it < NT; ++it) {
        const int j0 = it * 128;
        const int jn = (it == NT - 1) ? 0 : j0 + 128;   // branch-free clamp
        // ---- S^T (2 frags) ----
        f32x4 sA = MFMA16(kf0, qfS, zero);
        f32x4 sB = MFMA16(kf1, qfS, zero);
        kf0 = *(const bf16x8*)(kTb + (size_t)(jn + f0 * 16 + li) * CQ + 8 * g);
        kf1 = *(const bf16x8*)(kTb + (size_t)(jn + f1 * 16 + li) * CQ + 8 * g);
        float pa0 = exp2f(sA[0] - mrS), pa1 = exp2f(sA[1] - mrS);
        float pa2 = exp2f(sA[2] - mrS), pa3 = exp2f(sA[3] - mrS);
        float pb0 = exp2f(sB[0] - mrS), pb1 = exp2f(sB[1] - mrS);
        float pb2 = exp2f(sB[2] - mrS), pb3 = exp2f(sB[3] - mrS);
        ls += ((pa0 + pa1) + (pa2 + pa3)) + ((pb0 + pb1) + (pb2 + pb3));
        unsigned char* Pb = P[it & 1];
        u32x2 wA, wB;
        wA.x = pk_bf16(pa0, pa1); wA.y = pk_bf16(pa2, pa3);
        wB.x = pk_bf16(pb0, pb1); wB.y = pk_bf16(pb2, pb3);
        *(u32x2*)(Pb + pwOff0) = wA;
        *(u32x2*)(Pb + pwOff1) = wB;
        __syncthreads();
        // ---- prefetch next V (unconditional), then PV ----
        bf16x8 nv[2][4];
        #pragma unroll
        for (int cf = 0; cf < 2; ++cf)
            #pragma unroll
            for (int ks = 0; ks < 4; ++ks)
                nv[cf][ks] = *(const bf16x8*)(Vbb + (size_t)(cf * 16 + li) * NP + jn + ks * 32 + 8 * g);
        __builtin_amdgcn_s_setprio(1);
        #pragma unroll
        for (int ks = 0; ks < 4; ++ks) {
            const int o = (ks * 64 + 16 * g) ^ sw;
            bf16x8 p0 = *(const bf16x8*)(Pb + prRow0 + o);
            bf16x8 p1 = *(const bf16x8*)(Pb + prRow1 + o);
            acc[0][0] = MFMA16(p0, vf[0][ks], acc[0][0]);
            acc[0][1] = MFMA16(p0, vf[1][ks], acc[0][1]);
            acc[1][0] = MFMA16(p1, vf[0][ks], acc[1][0]);
            acc[1][1] = MFMA16(p1, vf[1][ks], acc[1][1]);
        }
        __builtin_amdgcn_s_setprio(0);
        #pragma unroll
        for (int cf = 0; cf < 2; ++cf)
            #pragma unroll
            for (int ks = 0; ks < 4; ++ks)
                vf[cf][ks] = nv[cf][ks];
    }

    // ---- denominator reduce (+ exact pad correction) ----
    ls += __shfl_xor(ls, 16); ls += __shfl_xor(ls, 32);
    if ((t & 63) < 16) red[w][li] = ls;
    __syncthreads();
    if (t < 32) {
        float s = red[(t >> 4) * 4 + 0][t & 15] + red[(t >> 4) * 4 + 1][t & 15]
                + red[(t >> 4) * 4 + 2][t & 15] + red[(t >> 4) * 4 + 3][t & 15];
        s -= 64.0f * exp2f(-qnorm[b * N_SP + i0 + t] * kmb);   // remove pad j's
        red_final[t] = s;
    }
    __syncthreads();

    // ---- epilogue: /ls, *gamma*INV_BOUND, + residual ----
    const float gsc = gamma_p[0] * INV_BOUND;
    #pragma unroll
    for (int qi = 0; qi < 2; ++qi) {
        f32x4 lsv = *(const f32x4*)(red_final + qi * 16 + 4 * g);
        f32x4 rinv;
        #pragma unroll
        for (int r = 0; r < 4; ++r) rinv[r] = gsc / lsv[r];
        #pragma unroll
        for (int cf = 0; cf < 2; ++cf) {
            const int c = cw + cf * 16 + li;
            const size_t base = ((size_t)b * C_CH + c) * N_SP + i0 + qi * 16 + 4 * g;
            float4 xv = *(const float4*)(x + base);
            float4 o;
            o.x = acc[qi][cf][0] * rinv[0] + xv.x;
            o.y = acc[qi][cf][1] * rinv[1] + xv.y;
            o.z = acc[qi][cf][2] * rinv[2] + xv.z;
            o.w = acc[qi][cf][3] * rinv[3] + xv.w;
            *(float4*)(out + base) = o;
        }
    }
}

// ---------------------------------------------------------------------------
extern "C" void kernel_launch(void* const* d_in, const int* in_sizes, int n_in,
                              void* d_out, int out_size, void* d_ws, size_t ws_size,
                              hipStream_t stream)
{
    const float* x  = (const float*)d_in[0];
    const float* Wq = (const float*)d_in[1];
    const float* bq = (const float*)d_in[2];
    const float* Wk = (const float*)d_in[3];
    const float* bk = (const float*)d_in[4];
    const float* Wv = (const float*)d_in[5];
    const float* bv = (const float*)d_in[6];
    const float* gm = (const float*)d_in[7];
    float* out = (float*)d_out;
    float* ws  = (float*)d_ws;

    float* scale = ws;                       // [0..3]
    float* kmax  = ws + 4;                   // [4..7], per-batch
    float* qnorm = ws + 8;                   // NB*N_SP floats
    u16* Wqb = (u16*)(ws + 8 + NB * N_SP);   // 16B-aligned (50208 % 16 == 0)
    u16* Wkb = Wqb + 32 * 256;
    u16* Wvb = Wkb + 32 * 256;
    u16* xT  = Wvb + 256 * 256;
    u16* qT  = xT + (size_t)NB * N_SP * C_CH;
    u16* kT  = qT + (size_t)NB * N_SP * CQ;
    u16* Vb  = kT + (size_t)NB * NP * CQ;

    (void)hipMemsetAsync(kmax, 0, NB * sizeof(float), stream);
    stage1_kernel<<<865, 256, 0, stream>>>(x, Wq, Wk, Wv, xT, Wqb, Wkb, Wvb, scale);
    qkv_mfma<<<984, 256, 0, stream>>>(xT, Wqb, Wkb, Wvb, bq, bk, bv, scale, qT, kT, Vb, qnorm, kmax);
    attn_mfma<<<392, 512, 0, stream>>>(qT, kT, Vb, x, gm, qnorm, kmax, out);
}

// Round 9
// 158.523 us; speedup vs baseline: 1.3101x; 1.0268x over previous
//
#include <hip/hip_runtime.h>

#define N_SP 3136   // H*W
#define NP   3200   // padded N (25 x 128)
#define NT   25     // attn j-tiles of 128
#define C_CH 256
#define CQ   32
#define NB   4
#define QT   48     // attn q-tile (66 tiles, q padded to 3168)
// 1 / (exp(sqrt(3))*sqrt(3136/256) + 2*sqrt(6))
#define INV_BOUND 0.04051569f
#define LOG2E 1.44269504f

typedef __attribute__((ext_vector_type(8))) short bf16x8;
typedef __attribute__((ext_vector_type(4))) float f32x4;
typedef unsigned short u16;
typedef unsigned int   u32;
typedef unsigned char  u8;
typedef long long      l64;

#define MFMA16(a,b,c) __builtin_amdgcn_mfma_f32_16x16x32_bf16(a,b,c,0,0,0)
#define MFMA8(a,b,c)  __builtin_amdgcn_mfma_f32_16x16x32_bf8_fp8(a,b,c,0,0,0)

__device__ __forceinline__ u16 f2b(float f) {
    u32 u = __builtin_bit_cast(u32, f);
    u += 0x7fffu + ((u >> 16) & 1u);   // RTNE
    return (u16)(u >> 16);
}
__device__ __forceinline__ u8 f2fp8(float f) {
    return (u8)(__builtin_amdgcn_cvt_pk_fp8_f32(f, f, 0, false) & 0xff);
}

// ---------------------------------------------------------------------------
// stage1: xT transpose (0..783, XCD-affine), W->bf16 (784..863), norm (864)
// ---------------------------------------------------------------------------
__global__ __launch_bounds__(256) void stage1_kernel(
    const float* __restrict__ x, const float* __restrict__ Wq,
    const float* __restrict__ Wk, const float* __restrict__ Wv,
    u16* __restrict__ xT, u16* __restrict__ Wqb, u16* __restrict__ Wkb,
    u16* __restrict__ Wvb, float* __restrict__ scale_out)
{
    __shared__ float smem[64 * 65];
    const int t = threadIdx.x;
    const int bid = blockIdx.x;

    if (bid < 784) {                       // xT[b][n][c] = bf16(x[b][c][n])
        float (*tile)[65] = (float(*)[65])smem;
        const int xcd = bid & 7, slot = bid >> 3;
        const int b = xcd >> 1;
        const int i = slot * 2 + (xcd & 1);          // 0..195
        const int ct = i & 3, nt = i >> 2;           // 4 x 49
        const int c0 = ct * 64, n0 = nt * 64;
        const int cc = t >> 4, nn4 = (t & 15) * 4;
        #pragma unroll
        for (int k = 0; k < 4; ++k) {
            int cl = cc + k * 16;
            float4 v = *(const float4*)(x + (size_t)(b * C_CH + c0 + cl) * N_SP + n0 + nn4);
            tile[cl][nn4] = v.x; tile[cl][nn4 + 1] = v.y;
            tile[cl][nn4 + 2] = v.z; tile[cl][nn4 + 3] = v.w;
        }
        __syncthreads();
        const int c4 = (t & 15) * 4, nn = t >> 4;
        #pragma unroll
        for (int k = 0; k < 4; ++k) {
            int nl = nn + k * 16;
            ushort4 o;
            o.x = f2b(tile[c4 + 0][nl]); o.y = f2b(tile[c4 + 1][nl]);
            o.z = f2b(tile[c4 + 2][nl]); o.w = f2b(tile[c4 + 3][nl]);
            *(ushort4*)(xT + (size_t)(b * N_SP + n0 + nl) * C_CH + c0 + c4) = o;
        }
    } else if (bid < 864) {                // W f32 -> bf16
        int idx = (bid - 784) * 256 + t;
        const float* src; u16* dst; int off;
        if (idx < 2048)      { src = Wq; dst = Wqb; off = idx; }
        else if (idx < 4096) { src = Wk; dst = Wkb; off = idx - 2048; }
        else                 { src = Wv; dst = Wvb; off = idx - 4096; }
        float4 v = *(const float4*)(src + off * 4);
        ushort4 o; o.x = f2b(v.x); o.y = f2b(v.y); o.z = f2b(v.z); o.w = f2b(v.w);
        *(ushort4*)(dst + off * 4) = o;
    } else {                               // norm -> scale
        float* red = smem;
        float u2 = 0.f;
        for (int i = t; i < CQ * C_CH; i += 256) { float w = Wq[i]; u2 += w * w; }
        red[t] = u2; __syncthreads();
        #pragma unroll
        for (int s = 128; s > 0; s >>= 1) { if (t < s) red[t] += red[t + s]; __syncthreads(); }
        float u2t = red[0]; __syncthreads();
        float vn2 = 0.f;
        for (int o = 0; o < CQ; ++o)   { float w = Wk[o * C_CH + t]; vn2 += w * w; }
        float wn2 = 0.f;
        for (int o = 0; o < C_CH; ++o) { float w = Wv[o * C_CH + t]; wn2 += w * w; }
        red[t] = fmaxf(vn2, wn2); __syncthreads();
        #pragma unroll
        for (int s = 128; s > 0; s >>= 1) { if (t < s) red[t] = fmaxf(red[t], red[t + s]); __syncthreads(); }
        if (t == 0) scale_out[0] = 1.0f / (sqrtf(u2t) * sqrtf(red[0]));
    }
}

// ---------------------------------------------------------------------------
// qkv via MFMA, XCD-affine (984 = 123 slots x 8). V output now fp8 e4m3.
// ---------------------------------------------------------------------------
__global__ __launch_bounds__(256) void qkv_mfma(
    const u16* __restrict__ xT, const u16* __restrict__ Wqb,
    const u16* __restrict__ Wkb, const u16* __restrict__ Wvb,
    const float* __restrict__ bq, const float* __restrict__ bk,
    const float* __restrict__ bv, const float* __restrict__ scale_p,
    u16* __restrict__ qT, u16* __restrict__ kT, u8* __restrict__ Vb,
    float* __restrict__ qnorm, float* __restrict__ kmax)
{
    const int t = threadIdx.x;
    const int xcd = blockIdx.x & 7, slot = blockIdx.x >> 3;
    const int b = xcd >> 1;
    const int i = slot * 2 + (xcd & 1);

    if (i >= 245) {                        // zero j-pad [3136, 3200) for batch b
        uint4 z = make_uint4(0u, 0u, 0u, 0u);
        *(uint4*)(kT + ((size_t)b * NP + 3136) * CQ + t * 8) = z;   // 64 rows x 32
        u8* vrow = Vb + ((size_t)b * C_CH + t) * NP + 3136;         // c = t, 64 B
        #pragma unroll
        for (int k = 0; k < 4; ++k) *(uint4*)(vrow + k * 16) = z;
        return;
    }

    const int split = i / 49, nt = i % 49;
    const int w = t >> 6, li = t & 15, g = (t >> 4) & 3;
    const int n = nt * 64 + w * 16 + li;
    const f32x4 zero = {0.f, 0.f, 0.f, 0.f};

    bf16x8 xf[8];
    #pragma unroll
    for (int ks = 0; ks < 8; ++ks)
        xf[ks] = *(const bf16x8*)(xT + (size_t)(b * N_SP + n) * C_CH + ks * 32 + 8 * g);

    if (split == 0) {
        f32x4 aq0 = zero, aq1 = zero, ak0 = zero, ak1 = zero;
        #pragma unroll
        for (int ks = 0; ks < 8; ++ks) {
            bf16x8 w0 = *(const bf16x8*)(Wqb + li * C_CH + ks * 32 + 8 * g);
            bf16x8 w1 = *(const bf16x8*)(Wqb + (16 + li) * C_CH + ks * 32 + 8 * g);
            bf16x8 w2 = *(const bf16x8*)(Wkb + li * C_CH + ks * 32 + 8 * g);
            bf16x8 w3 = *(const bf16x8*)(Wkb + (16 + li) * C_CH + ks * 32 + 8 * g);
            aq0 = MFMA16(w0, xf[ks], aq0);
            aq1 = MFMA16(w1, xf[ks], aq1);
            ak0 = MFMA16(w2, xf[ks], ak0);
            ak1 = MFMA16(w3, xf[ks], ak1);
        }
        const float scf = scale_p[0] * LOG2E;
        f32x4 bq0 = *(const f32x4*)(bq + 4 * g);
        f32x4 bq1 = *(const f32x4*)(bq + 16 + 4 * g);
        f32x4 bk0 = *(const f32x4*)(bk + 4 * g);
        f32x4 bk1 = *(const f32x4*)(bk + 16 + 4 * g);
        float qn2 = 0.f, kn2 = 0.f;
        ushort4 s0, s1;
        #pragma unroll
        for (int r = 0; r < 4; ++r) {
            float q0 = (aq0[r] + bq0[r]) * scf;
            float q1 = (aq1[r] + bq1[r]) * scf;
            qn2 += q0 * q0 + q1 * q1;
            ((u16*)&s0)[r] = f2b(q0); ((u16*)&s1)[r] = f2b(q1);
        }
        *(ushort4*)(qT + (size_t)(b * N_SP + n) * CQ + 4 * g)      = s0;
        *(ushort4*)(qT + (size_t)(b * N_SP + n) * CQ + 16 + 4 * g) = s1;
        #pragma unroll
        for (int r = 0; r < 4; ++r) {
            float k0 = ak0[r] + bk0[r];
            float k1 = ak1[r] + bk1[r];
            kn2 += k0 * k0 + k1 * k1;
            ((u16*)&s0)[r] = f2b(k0); ((u16*)&s1)[r] = f2b(k1);
        }
        *(ushort4*)(kT + (size_t)(b * NP + n) * CQ + 4 * g)      = s0;
        *(ushort4*)(kT + (size_t)(b * NP + n) * CQ + 16 + 4 * g) = s1;

        qn2 += __shfl_xor(qn2, 16); qn2 += __shfl_xor(qn2, 32);
        kn2 += __shfl_xor(kn2, 16); kn2 += __shfl_xor(kn2, 32);
        if (g == 0) qnorm[b * N_SP + n] = sqrtf(qn2);
        float kn = sqrtf(kn2);
        #pragma unroll
        for (int d = 1; d < 16; d <<= 1) kn = fmaxf(kn, __shfl_xor(kn, d));
        if ((t & 63) == 0) atomicMax((int*)(kmax + b), __float_as_int(kn));
    } else {
        const int r0 = (split - 1) * 64;
        f32x4 a[4] = {zero, zero, zero, zero};
        #pragma unroll
        for (int ks = 0; ks < 8; ++ks) {
            #pragma unroll
            for (int fr = 0; fr < 4; ++fr) {
                bf16x8 wf = *(const bf16x8*)(Wvb + (size_t)(r0 + fr * 16 + li) * C_CH + ks * 32 + 8 * g);
                a[fr] = MFMA16(wf, xf[ks], a[fr]);
            }
        }
        #pragma unroll
        for (int fr = 0; fr < 4; ++fr) {
            f32x4 bb = *(const f32x4*)(bv + r0 + fr * 16 + 4 * g);
            #pragma unroll
            for (int r = 0; r < 4; ++r)
                Vb[(size_t)(b * C_CH + r0 + fr * 16 + 4 * g + r) * NP + n] = f2fp8(a[fr][r] + bb[r]);
        }
    }
}

// ---------------------------------------------------------------------------
// Attention: 264 blocks (4b x 66 q-tiles of 48) x 512 thr (8 waves).
// Per 128-j tile: wave w computes S^T for j-frag w vs 3 q-frags (bf16 MFMA),
// p = exp2(S - qnorm*kmax) -> bf8 into padded-row LDS P (dbuf, 136B rows);
// after 1 barrier, PV = mfma_bf8_fp8(P, V_fp8) -> acc[3][2] (32 ch/wave).
// ---------------------------------------------------------------------------
__global__ __launch_bounds__(512, 4) void attn_mfma(
    const u16* __restrict__ qT, const u16* __restrict__ kT,
    const u8* __restrict__ Vb, const float* __restrict__ x,
    const float* __restrict__ gamma_p, const float* __restrict__ qnorm,
    const float* __restrict__ kmax, float* __restrict__ out)
{
    __shared__ __align__(16) u8 P[2][QT * 136];   // 13 KB dbuf, padded rows
    __shared__ float red[8][QT];
    __shared__ __align__(16) float red_final[QT];

    const int t = threadIdx.x;
    const int w = t >> 6, li = t & 15, g = (t >> 4) & 3;
    const int cw = w * 32;                   // PV channel base

    const int xcd = blockIdx.x & 7, idx = blockIdx.x >> 3;   // 264 = 8*33
    const int b = xcd >> 1;
    const int within = (xcd & 1) * 33 + idx;                 // 0..65
    const int i0 = within * QT;

    const u16* qTb = qT + (size_t)b * N_SP * CQ;
    const u16* kTb = kT + (size_t)b * NP * CQ;
    const u8*  Vbb = Vb + ((size_t)b * C_CH + cw) * NP;
    const float kmb = kmax[b];
    const f32x4 zero = {0.f, 0.f, 0.f, 0.f};

    bf16x8 qf[3]; float mr[3];
    #pragma unroll
    for (int qq = 0; qq < 3; ++qq) {
        int qr = i0 + qq * 16 + li;
        qr = qr < N_SP ? qr : N_SP - 1;                      // clamp pad rows
        qf[qq] = *(const bf16x8*)(qTb + (size_t)qr * CQ + 8 * g);
        mr[qq] = qnorm[b * N_SP + qr] * kmb;
    }

    f32x4 acc[3][2];
    #pragma unroll
    for (int qq = 0; qq < 3; ++qq) { acc[qq][0] = zero; acc[qq][1] = zero; }
    float ls[3] = {0.f, 0.f, 0.f};

    // prefetch tile 0
    bf16x8 kf = *(const bf16x8*)(kTb + (size_t)(w * 16 + li) * CQ + 8 * g);
    l64 vf[2][4];
    #pragma unroll
    for (int cf = 0; cf < 2; ++cf)
        #pragma unroll
        for (int ks = 0; ks < 4; ++ks)
            vf[cf][ks] = *(const l64*)(Vbb + (size_t)(cf * 16 + li) * NP + ks * 32 + 8 * g);

    #pragma unroll 2
    for (int it = 0; it < NT; ++it) {
        const int j0 = it * 128;
        const int jn = (it == NT - 1) ? 0 : j0 + 128;
        // ---- S^T: j-frag w x 3 q-frags ----
        f32x4 s0 = MFMA16(kf, qf[0], zero);
        f32x4 s1 = MFMA16(kf, qf[1], zero);
        f32x4 s2 = MFMA16(kf, qf[2], zero);
        kf = *(const bf16x8*)(kTb + (size_t)(jn + w * 16 + li) * CQ + 8 * g);
        u8* Pb = P[it & 1];
        const int pcol = w * 16 + 4 * g;
        {
            float p0 = exp2f(s0[0] - mr[0]), p1 = exp2f(s0[1] - mr[0]);
            float p2 = exp2f(s0[2] - mr[0]), p3 = exp2f(s0[3] - mr[0]);
            ls[0] += (p0 + p1) + (p2 + p3);
            int pk = __builtin_amdgcn_cvt_pk_bf8_f32(p0, p1, 0, false);
            pk = __builtin_amdgcn_cvt_pk_bf8_f32(p2, p3, pk, true);
            *(u32*)(Pb + (0 * 16 + li) * 136 + pcol) = (u32)pk;
        }
        {
            float p0 = exp2f(s1[0] - mr[1]), p1 = exp2f(s1[1] - mr[1]);
            float p2 = exp2f(s1[2] - mr[1]), p3 = exp2f(s1[3] - mr[1]);
            ls[1] += (p0 + p1) + (p2 + p3);
            int pk = __builtin_amdgcn_cvt_pk_bf8_f32(p0, p1, 0, false);
            pk = __builtin_amdgcn_cvt_pk_bf8_f32(p2, p3, pk, true);
            *(u32*)(Pb + (1 * 16 + li) * 136 + pcol) = (u32)pk;
        }
        {
            float p0 = exp2f(s2[0] - mr[2]), p1 = exp2f(s2[1] - mr[2]);
            float p2 = exp2f(s2[2] - mr[2]), p3 = exp2f(s2[3] - mr[2]);
            ls[2] += (p0 + p1) + (p2 + p3);
            int pk = __builtin_amdgcn_cvt_pk_bf8_f32(p0, p1, 0, false);
            pk = __builtin_amdgcn_cvt_pk_bf8_f32(p2, p3, pk, true);
            *(u32*)(Pb + (2 * 16 + li) * 136 + pcol) = (u32)pk;
        }
        __syncthreads();
        // ---- prefetch next V, then PV ----
        l64 nv[2][4];
        #pragma unroll
        for (int cf = 0; cf < 2; ++cf)
            #pragma unroll
            for (int ks = 0; ks < 4; ++ks)
                nv[cf][ks] = *(const l64*)(Vbb + (size_t)(cf * 16 + li) * NP + jn + ks * 32 + 8 * g);
        __builtin_amdgcn_s_setprio(1);
        #pragma unroll
        for (int ks = 0; ks < 4; ++ks) {
            const int o = ks * 32 + 8 * g;
            l64 pa0 = *(const l64*)(Pb + (0 * 16 + li) * 136 + o);
            l64 pa1 = *(const l64*)(Pb + (1 * 16 + li) * 136 + o);
            l64 pa2 = *(const l64*)(Pb + (2 * 16 + li) * 136 + o);
            acc[0][0] = MFMA8(pa0, vf[0][ks], acc[0][0]);
            acc[0][1] = MFMA8(pa0, vf[1][ks], acc[0][1]);
            acc[1][0] = MFMA8(pa1, vf[0][ks], acc[1][0]);
            acc[1][1] = MFMA8(pa1, vf[1][ks], acc[1][1]);
            acc[2][0] = MFMA8(pa2, vf[0][ks], acc[2][0]);
            acc[2][1] = MFMA8(pa2, vf[1][ks], acc[2][1]);
        }
        __builtin_amdgcn_s_setprio(0);
        #pragma unroll
        for (int cf = 0; cf < 2; ++cf)
            #pragma unroll
            for (int ks = 0; ks < 4; ++ks)
                vf[cf][ks] = nv[cf][ks];
    }

    // ---- denominator reduce (+ pad correction for 64 zero-k columns) ----
    #pragma unroll
    for (int qq = 0; qq < 3; ++qq) {
        ls[qq] += __shfl_xor(ls[qq], 16);
        ls[qq] += __shfl_xor(ls[qq], 32);
    }
    if ((t & 63) < 16) {
        red[w][0 * 16 + li] = ls[0];
        red[w][1 * 16 + li] = ls[1];
        red[w][2 * 16 + li] = ls[2];
    }
    __syncthreads();
    if (t < QT) {
        float s = 0.f;
        #pragma unroll
        for (int ww = 0; ww < 8; ++ww) s += red[ww][t];
        int qr = i0 + t; qr = qr < N_SP ? qr : N_SP - 1;
        s -= 64.0f * exp2f(-qnorm[b * N_SP + qr] * kmb);
        red_final[t] = s;
    }
    __syncthreads();

    // ---- epilogue: /ls, *gamma*INV_BOUND, + residual (guarded q) ----
    const float gsc = gamma_p[0] * INV_BOUND;
    #pragma unroll
    for (int qq = 0; qq < 3; ++qq) {
        if (i0 + qq * 16 >= N_SP) break;
        f32x4 lsv = *(const f32x4*)(red_final + qq * 16 + 4 * g);
        f32x4 rinv;
        #pragma unroll
        for (int r = 0; r < 4; ++r) rinv[r] = gsc / lsv[r];
        #pragma unroll
        for (int cf = 0; cf < 2; ++cf) {
            const int c = cw + cf * 16 + li;
            const size_t base = ((size_t)b * C_CH + c) * N_SP + i0 + qq * 16 + 4 * g;
            float4 xv = *(const float4*)(x + base);
            float4 o;
            o.x = acc[qq][cf][0] * rinv[0] + xv.x;
            o.y = acc[qq][cf][1] * rinv[1] + xv.y;
            o.z = acc[qq][cf][2] * rinv[2] + xv.z;
            o.w = acc[qq][cf][3] * rinv[3] + xv.w;
            *(float4*)(out + base) = o;
        }
    }
}

// ---------------------------------------------------------------------------
extern "C" void kernel_launch(void* const* d_in, const int* in_sizes, int n_in,
                              void* d_out, int out_size, void* d_ws, size_t ws_size,
                              hipStream_t stream)
{
    const float* x  = (const float*)d_in[0];
    const float* Wq = (const float*)d_in[1];
    const float* bq = (const float*)d_in[2];
    const float* Wk = (const float*)d_in[3];
    const float* bk = (const float*)d_in[4];
    const float* Wv = (const float*)d_in[5];
    const float* bv = (const float*)d_in[6];
    const float* gm = (const float*)d_in[7];
    float* out = (float*)d_out;
    float* ws  = (float*)d_ws;

    float* scale = ws;                       // [0..3]
    float* kmax  = ws + 4;                   // [4..7], per-batch
    float* qnorm = ws + 8;                   // NB*N_SP floats
    u16* Wqb = (u16*)(ws + 8 + NB * N_SP);   // 16B-aligned (50208 % 16 == 0)
    u16* Wkb = Wqb + 32 * 256;
    u16* Wvb = Wkb + 32 * 256;
    u16* xT  = Wvb + 256 * 256;
    u16* qT  = xT + (size_t)NB * N_SP * C_CH;
    u16* kT  = qT + (size_t)NB * N_SP * CQ;
    u8*  Vb  = (u8*)(kT + (size_t)NB * NP * CQ);

    (void)hipMemsetAsync(kmax, 0, NB * sizeof(float), stream);
    stage1_kernel<<<865, 256, 0, stream>>>(x, Wq, Wk, Wv, xT, Wqb, Wkb, Wvb, scale);
    qkv_mfma<<<984, 256, 0, stream>>>(xT, Wqb, Wkb, Wvb, bq, bk, bv, scale, qT, kT, Vb, qnorm, kmax);
    attn_mfma<<<264, 512, 0, stream>>>(qT, kT, Vb, x, gm, qnorm, kmax, out);
}

// Round 10
// 115.732 us; speedup vs baseline: 1.7945x; 1.3697x over previous
//
#include <hip/hip_runtime.h>

#define N_SP 3136   // H*W = 49*64
#define C_CH 256
#define CQ   32
#define NB   4
#define JT   64     // attn j-tile
#define NJT  49     // j-tiles (exact)
#define QT   64     // attn q-tile (49 tiles exact)
// 1 / (exp(sqrt(3))*sqrt(3136/256) + 2*sqrt(6))
#define INV_BOUND 0.04051569f
#define LOG2E 1.44269504f

typedef __attribute__((ext_vector_type(8))) short bf16x8;
typedef __attribute__((ext_vector_type(4))) float f32x4;
typedef unsigned short u16;
typedef unsigned int   u32;
typedef unsigned char  u8;
typedef long long      l64;

#define MFMA16(a,b,c) __builtin_amdgcn_mfma_f32_16x16x32_bf16(a,b,c,0,0,0)
#define MFMA8(a,b,c)  __builtin_amdgcn_mfma_f32_16x16x32_bf8_fp8(a,b,c,0,0,0)

__device__ __forceinline__ u16 f2b(float f) {
    u32 u = __builtin_bit_cast(u32, f);
    u += 0x7fffu + ((u >> 16) & 1u);   // RTNE
    return (u16)(u >> 16);
}
__device__ __forceinline__ u8 f2fp8(float f) {
    return (u8)(__builtin_amdgcn_cvt_pk_fp8_f32(f, f, 0, false) & 0xff);
}
__device__ __forceinline__ void dma16(const void* g, void* l) {
    __builtin_amdgcn_global_load_lds((const __attribute__((address_space(1))) u32*)g,
                                     (__attribute__((address_space(3))) u32*)l, 16, 0, 0);
}
__device__ __forceinline__ void dma4(const void* g, void* l) {
    __builtin_amdgcn_global_load_lds((const __attribute__((address_space(1))) u32*)g,
                                     (__attribute__((address_space(3))) u32*)l, 4, 0, 0);
}

// ---------------------------------------------------------------------------
// stage1: xT transpose (blocks 0..783), W->bf16 (784..863), norm (864)
// ---------------------------------------------------------------------------
__global__ __launch_bounds__(256) void stage1_kernel(
    const float* __restrict__ x, const float* __restrict__ Wq,
    const float* __restrict__ Wk, const float* __restrict__ Wv,
    u16* __restrict__ xT, u16* __restrict__ Wqb, u16* __restrict__ Wkb,
    u16* __restrict__ Wvb, float* __restrict__ scale_out)
{
    __shared__ float smem[64 * 65];
    const int t = threadIdx.x;
    const int bid = blockIdx.x;

    if (bid < 784) {
        float (*tile)[65] = (float(*)[65])smem;
        const int ct = bid & 3, nt = (bid >> 2) % 49, b = bid / 196;
        const int c0 = ct * 64, n0 = nt * 64;
        const int cc = t >> 4, nn4 = (t & 15) * 4;
        #pragma unroll
        for (int k = 0; k < 4; ++k) {
            int cl = cc + k * 16;
            float4 v = *(const float4*)(x + (size_t)(b * C_CH + c0 + cl) * N_SP + n0 + nn4);
            tile[cl][nn4] = v.x; tile[cl][nn4 + 1] = v.y;
            tile[cl][nn4 + 2] = v.z; tile[cl][nn4 + 3] = v.w;
        }
        __syncthreads();
        const int c4 = (t & 15) * 4, nn = t >> 4;
        #pragma unroll
        for (int k = 0; k < 4; ++k) {
            int nl = nn + k * 16;
            ushort4 o;
            o.x = f2b(tile[c4 + 0][nl]); o.y = f2b(tile[c4 + 1][nl]);
            o.z = f2b(tile[c4 + 2][nl]); o.w = f2b(tile[c4 + 3][nl]);
            *(ushort4*)(xT + (size_t)(b * N_SP + n0 + nl) * C_CH + c0 + c4) = o;
        }
    } else if (bid < 864) {
        int idx = (bid - 784) * 256 + t;
        const float* src; u16* dst; int off;
        if (idx < 2048)      { src = Wq; dst = Wqb; off = idx; }
        else if (idx < 4096) { src = Wk; dst = Wkb; off = idx - 2048; }
        else                 { src = Wv; dst = Wvb; off = idx - 4096; }
        float4 v = *(const float4*)(src + off * 4);
        ushort4 o; o.x = f2b(v.x); o.y = f2b(v.y); o.z = f2b(v.z); o.w = f2b(v.w);
        *(ushort4*)(dst + off * 4) = o;
    } else {
        float* red = smem;
        float u2 = 0.f;
        for (int i = t; i < CQ * C_CH; i += 256) { float w = Wq[i]; u2 += w * w; }
        red[t] = u2; __syncthreads();
        #pragma unroll
        for (int s = 128; s > 0; s >>= 1) { if (t < s) red[t] += red[t + s]; __syncthreads(); }
        float u2t = red[0]; __syncthreads();
        float vn2 = 0.f;
        for (int o = 0; o < CQ; ++o)   { float w = Wk[o * C_CH + t]; vn2 += w * w; }
        float wn2 = 0.f;
        for (int o = 0; o < C_CH; ++o) { float w = Wv[o * C_CH + t]; wn2 += w * w; }
        red[t] = fmaxf(vn2, wn2); __syncthreads();
        #pragma unroll
        for (int s = 128; s > 0; s >>= 1) { if (t < s) red[t] = fmaxf(red[t], red[t + s]); __syncthreads(); }
        if (t == 0) scale_out[0] = 1.0f / (sqrtf(u2t) * sqrtf(red[0]));
    }
}

// ---------------------------------------------------------------------------
// qkv via MFMA (980 blocks, 5-way row split). Outputs for the DMA attn:
//  kT: row n (64B, bf16) with 16B-granular XOR swizzle col ^= 16*(n&3)
//  Vb: fp8, byte col within 64-group swizzled: ^= 8*(ch&7)
//  qT plain (pre-scaled by scale*log2e), qnorm, kmax (atomicMax)
// ---------------------------------------------------------------------------
__global__ __launch_bounds__(256) void qkv_mfma(
    const u16* __restrict__ xT, const u16* __restrict__ Wqb,
    const u16* __restrict__ Wkb, const u16* __restrict__ Wvb,
    const float* __restrict__ bq, const float* __restrict__ bk,
    const float* __restrict__ bv, const float* __restrict__ scale_p,
    u16* __restrict__ qT, u16* __restrict__ kT, u8* __restrict__ Vb,
    float* __restrict__ qnorm, float* __restrict__ kmax)
{
    const int t = threadIdx.x;
    const int split = blockIdx.x / 196, tile = blockIdx.x % 196;
    const int b = tile / 49, nt = tile % 49;
    const int w = t >> 6, li = t & 15, g = (t >> 4) & 3;
    const int n = nt * 64 + w * 16 + li;
    const f32x4 zero = {0.f, 0.f, 0.f, 0.f};

    bf16x8 xf[8];
    #pragma unroll
    for (int ks = 0; ks < 8; ++ks)
        xf[ks] = *(const bf16x8*)(xT + (size_t)(b * N_SP + n) * C_CH + ks * 32 + 8 * g);

    if (split == 0) {
        f32x4 aq0 = zero, aq1 = zero, ak0 = zero, ak1 = zero;
        #pragma unroll
        for (int ks = 0; ks < 8; ++ks) {
            bf16x8 w0 = *(const bf16x8*)(Wqb + li * C_CH + ks * 32 + 8 * g);
            bf16x8 w1 = *(const bf16x8*)(Wqb + (16 + li) * C_CH + ks * 32 + 8 * g);
            bf16x8 w2 = *(const bf16x8*)(Wkb + li * C_CH + ks * 32 + 8 * g);
            bf16x8 w3 = *(const bf16x8*)(Wkb + (16 + li) * C_CH + ks * 32 + 8 * g);
            aq0 = MFMA16(w0, xf[ks], aq0);
            aq1 = MFMA16(w1, xf[ks], aq1);
            ak0 = MFMA16(w2, xf[ks], ak0);
            ak1 = MFMA16(w3, xf[ks], ak1);
        }
        const float scf = scale_p[0] * LOG2E;
        f32x4 bq0 = *(const f32x4*)(bq + 4 * g);
        f32x4 bq1 = *(const f32x4*)(bq + 16 + 4 * g);
        f32x4 bk0 = *(const f32x4*)(bk + 4 * g);
        f32x4 bk1 = *(const f32x4*)(bk + 16 + 4 * g);
        float qn2 = 0.f, kn2 = 0.f;
        ushort4 s0, s1;
        #pragma unroll
        for (int r = 0; r < 4; ++r) {
            float q0 = (aq0[r] + bq0[r]) * scf;
            float q1 = (aq1[r] + bq1[r]) * scf;
            qn2 += q0 * q0 + q1 * q1;
            ((u16*)&s0)[r] = f2b(q0); ((u16*)&s1)[r] = f2b(q1);
        }
        *(ushort4*)(qT + (size_t)(b * N_SP + n) * CQ + 4 * g)      = s0;
        *(ushort4*)(qT + (size_t)(b * N_SP + n) * CQ + 16 + 4 * g) = s1;
        #pragma unroll
        for (int r = 0; r < 4; ++r) {
            float k0 = ak0[r] + bk0[r];
            float k1 = ak1[r] + bk1[r];
            kn2 += k0 * k0 + k1 * k1;
            ((u16*)&s0)[r] = f2b(k0); ((u16*)&s1)[r] = f2b(k1);
        }
        // swizzled K row write (row stride 64B)
        u8* krow = (u8*)kT + (size_t)(b * N_SP + n) * 64;
        const int swk = 16 * (n & 3);
        *(ushort4*)(krow + ((8 * g) ^ swk))      = s0;
        *(ushort4*)(krow + ((32 + 8 * g) ^ swk)) = s1;

        qn2 += __shfl_xor(qn2, 16); qn2 += __shfl_xor(qn2, 32);
        kn2 += __shfl_xor(kn2, 16); kn2 += __shfl_xor(kn2, 32);
        if (g == 0) qnorm[b * N_SP + n] = sqrtf(qn2);
        float kn = sqrtf(kn2);
        #pragma unroll
        for (int d = 1; d < 16; d <<= 1) kn = fmaxf(kn, __shfl_xor(kn, d));
        if ((t & 63) == 0) atomicMax((int*)(kmax + b), __float_as_int(kn));
    } else {
        const int r0 = (split - 1) * 64;
        f32x4 a[4] = {zero, zero, zero, zero};
        #pragma unroll
        for (int ks = 0; ks < 8; ++ks) {
            #pragma unroll
            for (int fr = 0; fr < 4; ++fr) {
                bf16x8 wf = *(const bf16x8*)(Wvb + (size_t)(r0 + fr * 16 + li) * C_CH + ks * 32 + 8 * g);
                a[fr] = MFMA16(wf, xf[ks], a[fr]);
            }
        }
        const int nbase = n & ~63, noff = n & 63;
        #pragma unroll
        for (int fr = 0; fr < 4; ++fr) {
            f32x4 bb = *(const f32x4*)(bv + r0 + fr * 16 + 4 * g);
            #pragma unroll
            for (int r = 0; r < 4; ++r) {
                const int row = r0 + fr * 16 + 4 * g + r;
                Vb[(size_t)(b * C_CH + row) * N_SP + nbase + (noff ^ ((row & 7) << 3))]
                    = f2fp8(a[fr][r] + bb[r]);
            }
        }
    }
}

// ---------------------------------------------------------------------------
// Attention: 196 blocks (4b x 49 q-tiles of 64) x 512 thr (8 waves).
// Ring-3 DMA pipeline: V (fp8, 16KB/tile) + K (bf16 swz, 4KB/tile) via
// global_load_lds; counted s_waitcnt vmcnt(4); raw s_barrier; P (bf8) in LDS.
// Wave w: S^T j-frag (w&3) x q-frags {2(w>>2), +1}; PV: 32 ch x all 64 q.
// ---------------------------------------------------------------------------
__global__ __launch_bounds__(512) void attn_mfma(
    const u16* __restrict__ qT, const u16* __restrict__ kT,
    const u8* __restrict__ Vb, const float* __restrict__ x,
    const float* __restrict__ gamma_p, const float* __restrict__ qnorm,
    const float* __restrict__ kmax, float* __restrict__ out)
{
    __shared__ __align__(16) u8 smem[65536];
    // layout: V ring 3x16384 @0 | K ring 3x4096 @49152 | P 4096 @61440
    u8* const Vl = smem;
    u8* const Kl = smem + 49152;
    u8* const Pl = smem + 61440;
    float* const red       = (float*)(smem + 49152);        // overlay K after loop
    float* const red_final = (float*)(smem + 49152 + 1024);

    const int t = threadIdx.x;
    const int w = t >> 6, li = t & 15, g = (t >> 4) & 3;
    const int jh = w & 3, qh = w >> 2;
    const int cw = w * 32;
    const int sw8  = (li & 7) << 3;
    const int sw16 = (li & 3) << 4;

    const int b  = blockIdx.x / NJT;
    const int i0 = (blockIdx.x % NJT) * QT;

    const u16* qTb = qT + (size_t)b * N_SP * CQ;
    const u8*  kTb = (const u8*)kT + (size_t)b * N_SP * 64;
    const u8*  Vbb = Vb + (size_t)b * C_CH * N_SP;
    const float kmb = kmax[b];
    const f32x4 zero = {0.f, 0.f, 0.f, 0.f};

    const int qA = 2 * qh, qB = 2 * qh + 1;
    const bf16x8 qfA = *(const bf16x8*)(qTb + (size_t)(i0 + qA * 16 + li) * CQ + 8 * g);
    const bf16x8 qfB = *(const bf16x8*)(qTb + (size_t)(i0 + qB * 16 + li) * CQ + 8 * g);
    const float mrA = qnorm[b * N_SP + i0 + qA * 16 + li] * kmb;
    const float mrB = qnorm[b * N_SP + i0 + qB * 16 + li] * kmb;

    f32x4 acc[4][2];
    #pragma unroll
    for (int qq = 0; qq < 4; ++qq) { acc[qq][0] = zero; acc[qq][1] = zero; }
    float lsA = 0.f, lsB = 0.f;

    // DMA issue for tile jt into ring slot s (4 instr/thread, uniform)
    #define ISSUE(jt, s) {                                                        \
        const int jt_ = (jt); const int s_ = (s);                                 \
        _Pragma("unroll")                                                         \
        for (int i_ = 0; i_ < 2; ++i_) {                                          \
            int beta = i_ * 8192 + t * 16;                                        \
            dma16(Vbb + (size_t)(beta >> 6) * N_SP + jt_ * JT + (beta & 63),      \
                  Vl + s_ * 16384 + i_ * 8192 + w * 1024);                        \
        }                                                                         \
        _Pragma("unroll")                                                         \
        for (int i_ = 0; i_ < 2; ++i_) {                                          \
            int beta = i_ * 2048 + t * 4;                                         \
            dma4(kTb + (size_t)jt_ * 4096 + beta,                                 \
                 Kl + s_ * 4096 + i_ * 2048 + w * 256);                           \
        }                                                                         \
    }

    ISSUE(0, 0);
    ISSUE(1, 1);

    int cur = 0;
    for (int it = 0; it < NJT; ++it) {
        // wait tile `it` drained (issued 2 iters ago); tile it+1 stays in flight
        asm volatile("s_waitcnt vmcnt(4) lgkmcnt(0)" ::: "memory");
        __builtin_amdgcn_s_barrier();
        asm volatile("" ::: "memory");

        // issue tile it+2 into the slot whose readers just drained
        {
            int jn = it + 2; if (jn > NJT - 1) jn = NJT - 1;
            int s2 = cur + 2; if (s2 >= 3) s2 -= 3;
            ISSUE(jn, s2);
        }

        // ---- S^T: j-frag jh x q-frags {qA,qB} ----
        const u8* Kc = Kl + cur * 4096;
        bf16x8 kf = *(const bf16x8*)(Kc + (jh * 16 + li) * 64 + ((16 * g) ^ sw16));
        f32x4 sA = MFMA16(kf, qfA, zero);
        f32x4 sB = MFMA16(kf, qfB, zero);
        {
            float a0 = exp2f(sA[0] - mrA), a1 = exp2f(sA[1] - mrA);
            float a2 = exp2f(sA[2] - mrA), a3 = exp2f(sA[3] - mrA);
            lsA += (a0 + a1) + (a2 + a3);
            int pk = __builtin_amdgcn_cvt_pk_bf8_f32(a0, a1, 0, false);
            pk = __builtin_amdgcn_cvt_pk_bf8_f32(a2, a3, pk, true);
            *(u32*)(Pl + (qA * 16 + li) * 64 + ((jh * 16 + 4 * g) ^ sw8)) = (u32)pk;
            float b0 = exp2f(sB[0] - mrB), b1 = exp2f(sB[1] - mrB);
            float b2 = exp2f(sB[2] - mrB), b3 = exp2f(sB[3] - mrB);
            lsB += (b0 + b1) + (b2 + b3);
            pk = __builtin_amdgcn_cvt_pk_bf8_f32(b0, b1, 0, false);
            pk = __builtin_amdgcn_cvt_pk_bf8_f32(b2, b3, pk, true);
            *(u32*)(Pl + (qB * 16 + li) * 64 + ((jh * 16 + 4 * g) ^ sw8)) = (u32)pk;
        }
        asm volatile("s_waitcnt lgkmcnt(0)" ::: "memory");
        __builtin_amdgcn_s_barrier();
        asm volatile("" ::: "memory");

        // ---- PV: all 4 q-frags x this wave's 32 ch ----
        const u8* Vc = Vl + cur * 16384;
        __builtin_amdgcn_s_setprio(1);
        #pragma unroll
        for (int ks = 0; ks < 2; ++ks) {
            const int o = (ks * 32 + 8 * g);
            l64 pa0 = *(const l64*)(Pl + (0 * 16 + li) * 64 + (o ^ sw8));
            l64 pa1 = *(const l64*)(Pl + (1 * 16 + li) * 64 + (o ^ sw8));
            l64 pa2 = *(const l64*)(Pl + (2 * 16 + li) * 64 + (o ^ sw8));
            l64 pa3 = *(const l64*)(Pl + (3 * 16 + li) * 64 + (o ^ sw8));
            l64 vf0 = *(const l64*)(Vc + (cw + li) * 64 + (o ^ sw8));
            l64 vf1 = *(const l64*)(Vc + (cw + 16 + li) * 64 + (o ^ sw8));
            acc[0][0] = MFMA8(pa0, vf0, acc[0][0]);
            acc[0][1] = MFMA8(pa0, vf1, acc[0][1]);
            acc[1][0] = MFMA8(pa1, vf0, acc[1][0]);
            acc[1][1] = MFMA8(pa1, vf1, acc[1][1]);
            acc[2][0] = MFMA8(pa2, vf0, acc[2][0]);
            acc[2][1] = MFMA8(pa2, vf1, acc[2][1]);
            acc[3][0] = MFMA8(pa3, vf0, acc[3][0]);
            acc[3][1] = MFMA8(pa3, vf1, acc[3][1]);
        }
        __builtin_amdgcn_s_setprio(0);

        ++cur; if (cur == 3) cur = 0;
    }
    #undef ISSUE

    // ---- denominators ----
    lsA += __shfl_xor(lsA, 16); lsA += __shfl_xor(lsA, 32);
    lsB += __shfl_xor(lsB, 16); lsB += __shfl_xor(lsB, 32);
    __syncthreads();                       // drains DMAs + all waves done; K region reusable
    if ((t & 63) < 16) {
        red[w * 32 + 0 * 16 + li] = lsA;
        red[w * 32 + 1 * 16 + li] = lsB;
    }
    __syncthreads();
    if (t < 64) {
        const int h = t >> 4, l2 = t & 15;
        float s = 0.f;
        #pragma unroll
        for (int jw = 0; jw < 4; ++jw)
            s += red[((h >> 1) * 4 + jw) * 32 + (h & 1) * 16 + l2];
        red_final[t] = s;
    }
    __syncthreads();

    // ---- epilogue ----
    const float gsc = gamma_p[0] * INV_BOUND;
    #pragma unroll
    for (int qq = 0; qq < 4; ++qq) {
        f32x4 lsv = *(const f32x4*)(red_final + qq * 16 + 4 * g);
        f32x4 rinv;
        #pragma unroll
        for (int r = 0; r < 4; ++r) rinv[r] = gsc / lsv[r];
        #pragma unroll
        for (int cf = 0; cf < 2; ++cf) {
            const int c = cw + cf * 16 + li;
            const size_t base = ((size_t)b * C_CH + c) * N_SP + i0 + qq * 16 + 4 * g;
            float4 xv = *(const float4*)(x + base);
            float4 o;
            o.x = acc[qq][cf][0] * rinv[0] + xv.x;
            o.y = acc[qq][cf][1] * rinv[1] + xv.y;
            o.z = acc[qq][cf][2] * rinv[2] + xv.z;
            o.w = acc[qq][cf][3] * rinv[3] + xv.w;
            *(float4*)(out + base) = o;
        }
    }
}

// ---------------------------------------------------------------------------
extern "C" void kernel_launch(void* const* d_in, const int* in_sizes, int n_in,
                              void* d_out, int out_size, void* d_ws, size_t ws_size,
                              hipStream_t stream)
{
    const float* x  = (const float*)d_in[0];
    const float* Wq = (const float*)d_in[1];
    const float* bq = (const float*)d_in[2];
    const float* Wk = (const float*)d_in[3];
    const float* bk = (const float*)d_in[4];
    const float* Wv = (const float*)d_in[5];
    const float* bv = (const float*)d_in[6];
    const float* gm = (const float*)d_in[7];
    float* out = (float*)d_out;
    float* ws  = (float*)d_ws;

    float* scale = ws;                       // [0..3]
    float* kmax  = ws + 4;                   // [4..7]
    float* qnorm = ws + 8;                   // NB*N_SP
    u16* Wqb = (u16*)(ws + 8 + NB * N_SP);
    u16* Wkb = Wqb + 32 * 256;
    u16* Wvb = Wkb + 32 * 256;
    u16* xT  = Wvb + 256 * 256;
    u16* qT  = xT + (size_t)NB * N_SP * C_CH;
    u16* kT  = qT + (size_t)NB * N_SP * CQ;
    u8*  Vb  = (u8*)(kT + (size_t)NB * N_SP * CQ);

    (void)hipMemsetAsync(kmax, 0, NB * sizeof(float), stream);
    stage1_kernel<<<865, 256, 0, stream>>>(x, Wq, Wk, Wv, xT, Wqb, Wkb, Wvb, scale);
    qkv_mfma<<<980, 256, 0, stream>>>(xT, Wqb, Wkb, Wvb, bq, bk, bv, scale, qT, kT, Vb, qnorm, kmax);
    attn_mfma<<<NB * NJT, 512, 0, stream>>>(qT, kT, Vb, x, gm, qnorm, kmax, out);
}

// Round 11
// 101.415 us; speedup vs baseline: 2.0478x; 1.1412x over previous
//
#include <hip/hip_runtime.h>

#define N_SP 3136   // H*W = 49*64
#define C_CH 256
#define CQ   32
#define NB   4
#define JT   64     // attn j-tile
#define NJT  49     // j-tiles (exact)
#define QT   64     // attn q-tile (49 tiles exact)
// 1 / (exp(sqrt(3))*sqrt(3136/256) + 2*sqrt(6))
#define INV_BOUND 0.04051569f
#define LOG2E 1.44269504f

typedef __attribute__((ext_vector_type(8))) short bf16x8;
typedef __attribute__((ext_vector_type(4))) float f32x4;
typedef __attribute__((ext_vector_type(2))) long long l64x2;
typedef unsigned short u16;
typedef unsigned int   u32;
typedef unsigned char  u8;
typedef long long      l64;

#define MFMA16(a,b,c) __builtin_amdgcn_mfma_f32_16x16x32_bf16(a,b,c,0,0,0)
#define MFMA8(a,b,c)  __builtin_amdgcn_mfma_f32_16x16x32_bf8_fp8(a,b,c,0,0,0)

__device__ __forceinline__ u16 f2b(float f) {
    u32 u = __builtin_bit_cast(u32, f);
    u += 0x7fffu + ((u >> 16) & 1u);   // RTNE
    return (u16)(u >> 16);
}
__device__ __forceinline__ u8 f2fp8(float f) {
    return (u8)(__builtin_amdgcn_cvt_pk_fp8_f32(f, f, 0, false) & 0xff);
}
__device__ __forceinline__ void dma16(const void* g, void* l) {
    __builtin_amdgcn_global_load_lds((const __attribute__((address_space(1))) u32*)g,
                                     (__attribute__((address_space(3))) u32*)l, 16, 0, 0);
}
__device__ __forceinline__ void dma4(const void* g, void* l) {
    __builtin_amdgcn_global_load_lds((const __attribute__((address_space(1))) u32*)g,
                                     (__attribute__((address_space(3))) u32*)l, 4, 0, 0);
}

// ---------------------------------------------------------------------------
// stage1: xT transpose (0..783), W->bf16 (784..863), norm+scale+kmax0 (864)
// ---------------------------------------------------------------------------
__global__ __launch_bounds__(256) void stage1_kernel(
    const float* __restrict__ x, const float* __restrict__ Wq,
    const float* __restrict__ Wk, const float* __restrict__ Wv,
    u16* __restrict__ xT, u16* __restrict__ Wqb, u16* __restrict__ Wkb,
    u16* __restrict__ Wvb, float* __restrict__ scale_out,
    float* __restrict__ kmax)
{
    __shared__ float smem[64 * 65];
    const int t = threadIdx.x;
    const int bid = blockIdx.x;

    if (bid < 784) {
        float (*tile)[65] = (float(*)[65])smem;
        const int ct = bid & 3, nt = (bid >> 2) % 49, b = bid / 196;
        const int c0 = ct * 64, n0 = nt * 64;
        const int cc = t >> 4, nn4 = (t & 15) * 4;
        #pragma unroll
        for (int k = 0; k < 4; ++k) {
            int cl = cc + k * 16;
            float4 v = *(const float4*)(x + (size_t)(b * C_CH + c0 + cl) * N_SP + n0 + nn4);
            tile[cl][nn4] = v.x; tile[cl][nn4 + 1] = v.y;
            tile[cl][nn4 + 2] = v.z; tile[cl][nn4 + 3] = v.w;
        }
        __syncthreads();
        const int c4 = (t & 15) * 4, nn = t >> 4;
        #pragma unroll
        for (int k = 0; k < 4; ++k) {
            int nl = nn + k * 16;
            ushort4 o;
            o.x = f2b(tile[c4 + 0][nl]); o.y = f2b(tile[c4 + 1][nl]);
            o.z = f2b(tile[c4 + 2][nl]); o.w = f2b(tile[c4 + 3][nl]);
            *(ushort4*)(xT + (size_t)(b * N_SP + n0 + nl) * C_CH + c0 + c4) = o;
        }
    } else if (bid < 864) {
        int idx = (bid - 784) * 256 + t;
        const float* src; u16* dst; int off;
        if (idx < 2048)      { src = Wq; dst = Wqb; off = idx; }
        else if (idx < 4096) { src = Wk; dst = Wkb; off = idx - 2048; }
        else                 { src = Wv; dst = Wvb; off = idx - 4096; }
        float4 v = *(const float4*)(src + off * 4);
        ushort4 o; o.x = f2b(v.x); o.y = f2b(v.y); o.z = f2b(v.z); o.w = f2b(v.w);
        *(ushort4*)(dst + off * 4) = o;
    } else {
        if (t < NB) kmax[t] = 0.f;
        float* red = smem;
        float u2 = 0.f;
        for (int i = t; i < CQ * C_CH; i += 256) { float w = Wq[i]; u2 += w * w; }
        red[t] = u2; __syncthreads();
        #pragma unroll
        for (int s = 128; s > 0; s >>= 1) { if (t < s) red[t] += red[t + s]; __syncthreads(); }
        float u2t = red[0]; __syncthreads();
        float vn2 = 0.f;
        for (int o = 0; o < CQ; ++o)   { float w = Wk[o * C_CH + t]; vn2 += w * w; }
        float wn2 = 0.f;
        for (int o = 0; o < C_CH; ++o) { float w = Wv[o * C_CH + t]; wn2 += w * w; }
        red[t] = fmaxf(vn2, wn2); __syncthreads();
        #pragma unroll
        for (int s = 128; s > 0; s >>= 1) { if (t < s) red[t] = fmaxf(red[t], red[t + s]); __syncthreads(); }
        if (t == 0) scale_out[0] = 1.0f / (sqrtf(u2t) * sqrtf(red[0]));
    }
}

// ---------------------------------------------------------------------------
// qkv via MFMA (980 blocks, 5-way row split). DMA-friendly outputs:
//  Kg[b][n]: 64B row (32 bf16 ch), 16B-slot XOR swizzle ((n>>1)&3)<<4
//  Vg[b][jt]: contiguous 16KB [c][64B], byte p(j')=((j'>>5)&1)*8+((j'>>3)&3)*16
//             +(j'&7), XOR ((c>>1)&3)<<4
//  qT plain (pre-scaled by scale*log2e), qnorm, kmax (atomicMax)
// ---------------------------------------------------------------------------
__global__ __launch_bounds__(256) void qkv_mfma(
    const u16* __restrict__ xT, const u16* __restrict__ Wqb,
    const u16* __restrict__ Wkb, const u16* __restrict__ Wvb,
    const float* __restrict__ bq, const float* __restrict__ bk,
    const float* __restrict__ bv, const float* __restrict__ scale_p,
    u16* __restrict__ qT, u8* __restrict__ Kg, u8* __restrict__ Vg,
    float* __restrict__ qnorm, float* __restrict__ kmax)
{
    const int t = threadIdx.x;
    const int split = blockIdx.x / 196, tile = blockIdx.x % 196;
    const int b = tile / 49, nt = tile % 49;
    const int w = t >> 6, li = t & 15, g = (t >> 4) & 3;
    const int n = nt * 64 + w * 16 + li;
    const f32x4 zero = {0.f, 0.f, 0.f, 0.f};

    bf16x8 xf[8];
    #pragma unroll
    for (int ks = 0; ks < 8; ++ks)
        xf[ks] = *(const bf16x8*)(xT + (size_t)(b * N_SP + n) * C_CH + ks * 32 + 8 * g);

    if (split == 0) {
        f32x4 aq0 = zero, aq1 = zero, ak0 = zero, ak1 = zero;
        #pragma unroll
        for (int ks = 0; ks < 8; ++ks) {
            bf16x8 w0 = *(const bf16x8*)(Wqb + li * C_CH + ks * 32 + 8 * g);
            bf16x8 w1 = *(const bf16x8*)(Wqb + (16 + li) * C_CH + ks * 32 + 8 * g);
            bf16x8 w2 = *(const bf16x8*)(Wkb + li * C_CH + ks * 32 + 8 * g);
            bf16x8 w3 = *(const bf16x8*)(Wkb + (16 + li) * C_CH + ks * 32 + 8 * g);
            aq0 = MFMA16(w0, xf[ks], aq0);
            aq1 = MFMA16(w1, xf[ks], aq1);
            ak0 = MFMA16(w2, xf[ks], ak0);
            ak1 = MFMA16(w3, xf[ks], ak1);
        }
        const float scf = scale_p[0] * LOG2E;
        f32x4 bq0 = *(const f32x4*)(bq + 4 * g);
        f32x4 bq1 = *(const f32x4*)(bq + 16 + 4 * g);
        f32x4 bk0 = *(const f32x4*)(bk + 4 * g);
        f32x4 bk1 = *(const f32x4*)(bk + 16 + 4 * g);
        float qn2 = 0.f, kn2 = 0.f;
        ushort4 s0, s1;
        #pragma unroll
        for (int r = 0; r < 4; ++r) {
            float q0 = (aq0[r] + bq0[r]) * scf;
            float q1 = (aq1[r] + bq1[r]) * scf;
            qn2 += q0 * q0 + q1 * q1;
            ((u16*)&s0)[r] = f2b(q0); ((u16*)&s1)[r] = f2b(q1);
        }
        *(ushort4*)(qT + (size_t)(b * N_SP + n) * CQ + 4 * g)      = s0;
        *(ushort4*)(qT + (size_t)(b * N_SP + n) * CQ + 16 + 4 * g) = s1;
        #pragma unroll
        for (int r = 0; r < 4; ++r) {
            float k0 = ak0[r] + bk0[r];
            float k1 = ak1[r] + bk1[r];
            kn2 += k0 * k0 + k1 * k1;
            ((u16*)&s0)[r] = f2b(k0); ((u16*)&s1)[r] = f2b(k1);
        }
        u8* krow = Kg + ((size_t)b * N_SP + n) * 64;
        const int swn = ((n >> 1) & 3) << 4;
        *(ushort4*)(krow + ((8 * g) ^ swn))      = s0;
        *(ushort4*)(krow + ((32 + 8 * g) ^ swn)) = s1;

        qn2 += __shfl_xor(qn2, 16); qn2 += __shfl_xor(qn2, 32);
        kn2 += __shfl_xor(kn2, 16); kn2 += __shfl_xor(kn2, 32);
        if (g == 0) qnorm[b * N_SP + n] = sqrtf(qn2);
        float kn = sqrtf(kn2);
        #pragma unroll
        for (int d = 1; d < 16; d <<= 1) kn = fmaxf(kn, __shfl_xor(kn, d));
        if ((t & 63) == 0) atomicMax((int*)(kmax + b), __float_as_int(kn));
    } else {
        const int r0 = (split - 1) * 64;
        f32x4 a[4] = {zero, zero, zero, zero};
        #pragma unroll
        for (int ks = 0; ks < 8; ++ks) {
            #pragma unroll
            for (int fr = 0; fr < 4; ++fr) {
                bf16x8 wf = *(const bf16x8*)(Wvb + (size_t)(r0 + fr * 16 + li) * C_CH + ks * 32 + 8 * g);
                a[fr] = MFMA16(wf, xf[ks], a[fr]);
            }
        }
        // byte position for this thread's j' = w*16+li within tile nt
        const int jj = w * 16 + li;
        const int p = ((jj >> 5) & 1) * 8 + ((jj >> 3) & 3) * 16 + (jj & 7);
        u8* vtile = Vg + (size_t)(b * NJT + nt) * 16384;
        #pragma unroll
        for (int fr = 0; fr < 4; ++fr) {
            f32x4 bb = *(const f32x4*)(bv + r0 + fr * 16 + 4 * g);
            #pragma unroll
            for (int r = 0; r < 4; ++r) {
                const int c = r0 + fr * 16 + 4 * g + r;
                vtile[c * 64 + (p ^ (((c >> 1) & 3) << 4))] = f2fp8(a[fr][r] + bb[r]);
            }
        }
    }
}

// ---------------------------------------------------------------------------
// Attention: 196 blocks (4b x 49 q-tiles of 64) x 512 thr (8 waves).
// Ring-4 DMA pipeline (depth 3, vmcnt(8)), fully COALESCED sources:
// V tile = contiguous 16KB, K tile = contiguous 4KB. All LDS reads b128,
// swizzle ((row>>1)&3)<<4 => max 2-way bank aliasing (free).
// ---------------------------------------------------------------------------
__global__ __launch_bounds__(512) void attn_mfma(
    const u16* __restrict__ qT, const u8* __restrict__ Kg,
    const u8* __restrict__ Vg, const float* __restrict__ x,
    const float* __restrict__ gamma_p, const float* __restrict__ qnorm,
    const float* __restrict__ kmax, float* __restrict__ out)
{
    __shared__ __align__(16) u8 smem[86016];
    u8* const Vl = smem;             // 4 x 16384
    u8* const Kl = smem + 65536;     // 4 x 4096
    u8* const Pl = smem + 81920;     // 4096 (reduce overlays here after loop)

    const int t = threadIdx.x;
    const int w = t >> 6, li = t & 15, g = (t >> 4) & 3;
    const int jh = w & 3, qh = w >> 2;
    const int cw = w * 32;
    const int swz = ((li >> 1) & 3) << 4;

    const int b  = blockIdx.x / NJT;
    const int i0 = (blockIdx.x % NJT) * QT;

    const u16* qTb = qT + (size_t)b * N_SP * CQ;
    const u8*  Kbb = Kg + (size_t)b * N_SP * 64;
    const u8*  Vbb = Vg + (size_t)b * NJT * 16384;
    const float kmb = kmax[b];
    const f32x4 zero = {0.f, 0.f, 0.f, 0.f};

    const int qA = 2 * qh, qB = 2 * qh + 1;
    const bf16x8 qfA = *(const bf16x8*)(qTb + (size_t)(i0 + qA * 16 + li) * CQ + 8 * g);
    const bf16x8 qfB = *(const bf16x8*)(qTb + (size_t)(i0 + qB * 16 + li) * CQ + 8 * g);
    const float mrA = qnorm[b * N_SP + i0 + qA * 16 + li] * kmb;
    const float mrB = qnorm[b * N_SP + i0 + qB * 16 + li] * kmb;

    f32x4 acc[4][2];
    #pragma unroll
    for (int qq = 0; qq < 4; ++qq) { acc[qq][0] = zero; acc[qq][1] = zero; }
    float lsA = 0.f, lsB = 0.f;

    #define ISSUE(jt_, s_) do {                                               \
        const u8* vsrc_ = Vbb + (size_t)(jt_) * 16384;                        \
        const u8* ksrc_ = Kbb + (size_t)(jt_) * 4096;                         \
        _Pragma("unroll")                                                     \
        for (int i_ = 0; i_ < 2; ++i_)                                        \
            dma16(vsrc_ + i_ * 8192 + t * 16,                                 \
                  Vl + (s_) * 16384 + i_ * 8192 + w * 1024);                  \
        _Pragma("unroll")                                                     \
        for (int i_ = 0; i_ < 2; ++i_)                                        \
            dma4(ksrc_ + i_ * 2048 + t * 4,                                   \
                 Kl + (s_) * 4096 + i_ * 2048 + w * 256);                     \
    } while (0)

    ISSUE(0, 0);
    ISSUE(1, 1);
    ISSUE(2, 2);

    // P write position (fixed per thread): j' = jh*16 + 4g + r
    const int p0 = ((jh >> 1) & 1) * 8 + ((jh * 2 + (g >> 1)) & 3) * 16 + 4 * (g & 1);

    for (int it = 0; it < NJT; ++it) {
        const int cur = it & 3;
        asm volatile("s_waitcnt vmcnt(8) lgkmcnt(0)" ::: "memory");
        __builtin_amdgcn_s_barrier();
        asm volatile("" ::: "memory");

        {
            int jn = it + 3; if (jn > NJT - 1) jn = NJT - 1;
            ISSUE(jn, (cur + 3) & 3);
        }

        // ---- S^T: j-frag jh x q-frags {qA, qB} ----
        const u8* Kc = Kl + cur * 4096;
        bf16x8 kf = *(const bf16x8*)(Kc + (jh * 16 + li) * 64 + ((16 * g) ^ swz));
        f32x4 sA = MFMA16(kf, qfA, zero);
        f32x4 sB = MFMA16(kf, qfB, zero);
        {
            float a0 = exp2f(sA[0] - mrA), a1 = exp2f(sA[1] - mrA);
            float a2 = exp2f(sA[2] - mrA), a3 = exp2f(sA[3] - mrA);
            lsA += (a0 + a1) + (a2 + a3);
            int pk = __builtin_amdgcn_cvt_pk_bf8_f32(a0, a1, 0, false);
            pk = __builtin_amdgcn_cvt_pk_bf8_f32(a2, a3, pk, true);
            *(u32*)(Pl + (qA * 16 + li) * 64 + (p0 ^ swz)) = (u32)pk;
            float b0 = exp2f(sB[0] - mrB), b1 = exp2f(sB[1] - mrB);
            float b2 = exp2f(sB[2] - mrB), b3 = exp2f(sB[3] - mrB);
            lsB += (b0 + b1) + (b2 + b3);
            pk = __builtin_amdgcn_cvt_pk_bf8_f32(b0, b1, 0, false);
            pk = __builtin_amdgcn_cvt_pk_bf8_f32(b2, b3, pk, true);
            *(u32*)(Pl + (qB * 16 + li) * 64 + (p0 ^ swz)) = (u32)pk;
        }
        asm volatile("s_waitcnt lgkmcnt(0)" ::: "memory");
        __builtin_amdgcn_s_barrier();
        asm volatile("" ::: "memory");

        // ---- PV: all 4 q-frags x this wave's 32 ch (b128 = both ks) ----
        const u8* Vc = Vl + cur * 16384;
        __builtin_amdgcn_s_setprio(1);
        l64x2 pa0 = *(const l64x2*)(Pl + (0 * 16 + li) * 64 + ((16 * g) ^ swz));
        l64x2 pa1 = *(const l64x2*)(Pl + (1 * 16 + li) * 64 + ((16 * g) ^ swz));
        l64x2 pa2 = *(const l64x2*)(Pl + (2 * 16 + li) * 64 + ((16 * g) ^ swz));
        l64x2 pa3 = *(const l64x2*)(Pl + (3 * 16 + li) * 64 + ((16 * g) ^ swz));
        l64x2 v0  = *(const l64x2*)(Vc + (cw + li) * 64 + ((16 * g) ^ swz));
        l64x2 v1  = *(const l64x2*)(Vc + (cw + 16 + li) * 64 + ((16 * g) ^ swz));
        acc[0][0] = MFMA8(pa0[0], v0[0], acc[0][0]);
        acc[0][1] = MFMA8(pa0[0], v1[0], acc[0][1]);
        acc[1][0] = MFMA8(pa1[0], v0[0], acc[1][0]);
        acc[1][1] = MFMA8(pa1[0], v1[0], acc[1][1]);
        acc[2][0] = MFMA8(pa2[0], v0[0], acc[2][0]);
        acc[2][1] = MFMA8(pa2[0], v1[0], acc[2][1]);
        acc[3][0] = MFMA8(pa3[0], v0[0], acc[3][0]);
        acc[3][1] = MFMA8(pa3[0], v1[0], acc[3][1]);
        acc[0][0] = MFMA8(pa0[1], v0[1], acc[0][0]);
        acc[0][1] = MFMA8(pa0[1], v1[1], acc[0][1]);
        acc[1][0] = MFMA8(pa1[1], v0[1], acc[1][0]);
        acc[1][1] = MFMA8(pa1[1], v1[1], acc[1][1]);
        acc[2][0] = MFMA8(pa2[1], v0[1], acc[2][0]);
        acc[2][1] = MFMA8(pa2[1], v1[1], acc[2][1]);
        acc[3][0] = MFMA8(pa3[1], v0[1], acc[3][0]);
        acc[3][1] = MFMA8(pa3[1], v1[1], acc[3][1]);
        __builtin_amdgcn_s_setprio(0);
    }
    #undef ISSUE

    // ---- denominators (reduce buffers overlay P region; safe re DMA) ----
    lsA += __shfl_xor(lsA, 16); lsA += __shfl_xor(lsA, 32);
    lsB += __shfl_xor(lsB, 16); lsB += __shfl_xor(lsB, 32);
    __syncthreads();
    float* red       = (float*)Pl;
    float* red_final = (float*)(Pl + 1024);
    if ((t & 63) < 16) {
        red[w * 32 + li]      = lsA;
        red[w * 32 + 16 + li] = lsB;
    }
    __syncthreads();
    if (t < 64) {
        const int h = t >> 4, l2 = t & 15;
        float s = 0.f;
        #pragma unroll
        for (int jw = 0; jw < 4; ++jw)
            s += red[((h >> 1) * 4 + jw) * 32 + (h & 1) * 16 + l2];
        red_final[t] = s;
    }
    __syncthreads();

    // ---- epilogue ----
    const float gsc = gamma_p[0] * INV_BOUND;
    #pragma unroll
    for (int qq = 0; qq < 4; ++qq) {
        f32x4 lsv = *(const f32x4*)(red_final + qq * 16 + 4 * g);
        f32x4 rinv;
        #pragma unroll
        for (int r = 0; r < 4; ++r) rinv[r] = gsc / lsv[r];
        #pragma unroll
        for (int cf = 0; cf < 2; ++cf) {
            const int c = cw + cf * 16 + li;
            const size_t base = ((size_t)b * C_CH + c) * N_SP + i0 + qq * 16 + 4 * g;
            float4 xv = *(const float4*)(x + base);
            float4 o;
            o.x = acc[qq][cf][0] * rinv[0] + xv.x;
            o.y = acc[qq][cf][1] * rinv[1] + xv.y;
            o.z = acc[qq][cf][2] * rinv[2] + xv.z;
            o.w = acc[qq][cf][3] * rinv[3] + xv.w;
            *(float4*)(out + base) = o;
        }
    }
}

// ---------------------------------------------------------------------------
extern "C" void kernel_launch(void* const* d_in, const int* in_sizes, int n_in,
                              void* d_out, int out_size, void* d_ws, size_t ws_size,
                              hipStream_t stream)
{
    const float* x  = (const float*)d_in[0];
    const float* Wq = (const float*)d_in[1];
    const float* bq = (const float*)d_in[2];
    const float* Wk = (const float*)d_in[3];
    const float* bk = (const float*)d_in[4];
    const float* Wv = (const float*)d_in[5];
    const float* bv = (const float*)d_in[6];
    const float* gm = (const float*)d_in[7];
    float* out = (float*)d_out;
    float* ws  = (float*)d_ws;

    float* scale = ws;                       // [0..3]
    float* kmax  = ws + 4;                   // [4..7]
    float* qnorm = ws + 8;                   // NB*N_SP
    u16* Wqb = (u16*)(ws + 8 + NB * N_SP);
    u16* Wkb = Wqb + 32 * 256;
    u16* Wvb = Wkb + 32 * 256;
    u16* xT  = Wvb + 256 * 256;
    u16* qT  = xT + (size_t)NB * N_SP * C_CH;
    u8*  Kg  = (u8*)(qT + (size_t)NB * N_SP * CQ);
    u8*  Vg  = Kg + (size_t)NB * N_SP * 64;

    stage1_kernel<<<865, 256, 0, stream>>>(x, Wq, Wk, Wv, xT, Wqb, Wkb, Wvb, scale, kmax);
    qkv_mfma<<<980, 256, 0, stream>>>(xT, Wqb, Wkb, Wvb, bq, bk, bv, scale, qT, Kg, Vg, qnorm, kmax);
    attn_mfma<<<NB * NJT, 512, 0, stream>>>(qT, Kg, Vg, x, gm, qnorm, kmax, out);
}

// Round 12
// 87.920 us; speedup vs baseline: 2.3621x; 1.1535x over previous
//
#include <hip/hip_runtime.h>

#define N_SP 3136   // H*W = 49*64
#define C_CH 256
#define CQ   32
#define NB   4
#define JT   64     // attn j-tile
#define NJT  49     // j-tiles (exact)
#define QT   64     // attn q-tile (49 tiles exact)
// 1 / (exp(sqrt(3))*sqrt(3136/256) + 2*sqrt(6))
#define INV_BOUND 0.04051569f
#define LOG2E 1.44269504f

typedef __attribute__((ext_vector_type(8))) short bf16x8;
typedef __attribute__((ext_vector_type(4))) float f32x4;
typedef __attribute__((ext_vector_type(2))) long long l64x2;
typedef unsigned short u16;
typedef unsigned int   u32;
typedef unsigned char  u8;
typedef long long      l64;

#define MFMA16(a,b,c) __builtin_amdgcn_mfma_f32_16x16x32_bf16(a,b,c,0,0,0)
#define MFMA8(a,b,c)  __builtin_amdgcn_mfma_f32_16x16x32_bf8_fp8(a,b,c,0,0,0)

__device__ __forceinline__ u16 f2b(float f) {
    u32 u = __builtin_bit_cast(u32, f);
    u += 0x7fffu + ((u >> 16) & 1u);   // RTNE
    return (u16)(u >> 16);
}
__device__ __forceinline__ u8 f2fp8(float f) {
    return (u8)(__builtin_amdgcn_cvt_pk_fp8_f32(f, f, 0, false) & 0xff);
}
__device__ __forceinline__ void dma16(const void* g, void* l) {
    __builtin_amdgcn_global_load_lds((const __attribute__((address_space(1))) u32*)g,
                                     (__attribute__((address_space(3))) u32*)l, 16, 0, 0);
}
__device__ __forceinline__ void dma4(const void* g, void* l) {
    __builtin_amdgcn_global_load_lds((const __attribute__((address_space(1))) u32*)g,
                                     (__attribute__((address_space(3))) u32*)l, 4, 0, 0);
}

// ---------------------------------------------------------------------------
// stage1: xT transpose (0..783), W->bf16 (784..863), norm+scale+kmax0 (864).
// xT and W are stored PRE-SWIZZLED: within each 512B row r, the 16B slot at
// nominal byte o is stored at o ^ ((r&15)<<5)  (qkv DMAs linearly, reads XOR).
// ---------------------------------------------------------------------------
__global__ __launch_bounds__(256) void stage1_kernel(
    const float* __restrict__ x, const float* __restrict__ Wq,
    const float* __restrict__ Wk, const float* __restrict__ Wv,
    u8* __restrict__ xT, u8* __restrict__ Wqb, u8* __restrict__ Wkb,
    u8* __restrict__ Wvb, float* __restrict__ scale_out,
    float* __restrict__ kmax)
{
    __shared__ float smem[64 * 65];
    const int t = threadIdx.x;
    const int bid = blockIdx.x;

    if (bid < 784) {
        float (*tile)[65] = (float(*)[65])smem;
        const int ct = bid & 3, nt = (bid >> 2) % 49, b = bid / 196;
        const int c0 = ct * 64, n0 = nt * 64;
        const int cc = t >> 4, nn4 = (t & 15) * 4;
        #pragma unroll
        for (int k = 0; k < 4; ++k) {
            int cl = cc + k * 16;
            float4 v = *(const float4*)(x + (size_t)(b * C_CH + c0 + cl) * N_SP + n0 + nn4);
            tile[cl][nn4] = v.x; tile[cl][nn4 + 1] = v.y;
            tile[cl][nn4 + 2] = v.z; tile[cl][nn4 + 3] = v.w;
        }
        __syncthreads();
        const int c4 = (t & 15) * 4, nn = t >> 4;
        #pragma unroll
        for (int k = 0; k < 4; ++k) {
            int nl = nn + k * 16;
            ushort4 o;
            o.x = f2b(tile[c4 + 0][nl]); o.y = f2b(tile[c4 + 1][nl]);
            o.z = f2b(tile[c4 + 2][nl]); o.w = f2b(tile[c4 + 3][nl]);
            const int off = ((c0 + c4) * 2) ^ ((nl & 15) << 5);
            *(ushort4*)(xT + (size_t)(b * N_SP + n0 + nl) * 512 + off) = o;
        }
    } else if (bid < 864) {
        int idx = (bid - 784) * 256 + t;
        const float* src; u8* dst; int off;
        if (idx < 2048)      { src = Wq; dst = Wqb; off = idx; }
        else if (idx < 4096) { src = Wk; dst = Wkb; off = idx - 2048; }
        else                 { src = Wv; dst = Wvb; off = idx - 4096; }
        float4 v = *(const float4*)(src + off * 4);
        ushort4 o; o.x = f2b(v.x); o.y = f2b(v.y); o.z = f2b(v.z); o.w = f2b(v.w);
        const int row = off >> 6, inner = (off & 63) * 8;
        *(ushort4*)(dst + row * 512 + (inner ^ ((row & 15) << 5))) = o;
    } else {
        if (t < NB) kmax[t] = 0.f;
        float* red = smem;
        float u2 = 0.f;
        for (int i = t; i < CQ * C_CH; i += 256) { float w = Wq[i]; u2 += w * w; }
        red[t] = u2; __syncthreads();
        #pragma unroll
        for (int s = 128; s > 0; s >>= 1) { if (t < s) red[t] += red[t + s]; __syncthreads(); }
        float u2t = red[0]; __syncthreads();
        float vn2 = 0.f;
        for (int o = 0; o < CQ; ++o)   { float w = Wk[o * C_CH + t]; vn2 += w * w; }
        float wn2 = 0.f;
        for (int o = 0; o < C_CH; ++o) { float w = Wv[o * C_CH + t]; wn2 += w * w; }
        red[t] = fmaxf(vn2, wn2); __syncthreads();
        #pragma unroll
        for (int s = 128; s > 0; s >>= 1) { if (t < s) red[t] = fmaxf(red[t], red[t + s]); __syncthreads(); }
        if (t == 0) scale_out[0] = 1.0f / (sqrtf(u2t) * sqrtf(red[0]));
    }
}

// ---------------------------------------------------------------------------
// qkv via MFMA (980 blocks, 5-way row split) — DMA-staged operands:
// x tile (32KB) + W slice (32KB) -> LDS via global_load_lds, one barrier,
// then pure LDS b128 reads (XOR (row&15)<<5, 2-way max) + MFMA.
// Outputs unchanged: qT plain, Kg (attn layout), Vg (fp8 attn tiles),
// qnorm, kmax(atomicMax).
// ---------------------------------------------------------------------------
__global__ __launch_bounds__(256) void qkv_mfma(
    const u8* __restrict__ xT, const u8* __restrict__ Wqb,
    const u8* __restrict__ Wkb, const u8* __restrict__ Wvb,
    const float* __restrict__ bq, const float* __restrict__ bk,
    const float* __restrict__ bv, const float* __restrict__ scale_p,
    u16* __restrict__ qT, u8* __restrict__ Kg, u8* __restrict__ Vg,
    float* __restrict__ qnorm, float* __restrict__ kmax)
{
    __shared__ __align__(16) u8 xTl[32768];
    __shared__ __align__(16) u8 Wl[32768];

    const int t = threadIdx.x;
    const int split = blockIdx.x / 196, tile = blockIdx.x % 196;
    const int b = tile / 49, nt = tile % 49;
    const int w = t >> 6, lane = t & 63, li = t & 15, g = (t >> 4) & 3;
    const int n = nt * 64 + w * 16 + li;
    const int r0 = (split - 1) * 64;
    const f32x4 zero = {0.f, 0.f, 0.f, 0.f};

    // ---- DMA stage: x tile + W slice ----
    {
        const u8* xsrc = xT + (size_t)(b * N_SP + nt * 64) * 512;
        #pragma unroll
        for (int i = 0; i < 8; ++i)
            dma16(xsrc + w * 8192 + i * 1024 + lane * 16, xTl + w * 8192 + i * 1024);
        if (split == 0) {
            #pragma unroll
            for (int i = 0; i < 4; ++i)
                dma16(Wqb + w * 4096 + i * 1024 + lane * 16, Wl + w * 4096 + i * 1024);
            #pragma unroll
            for (int i = 0; i < 4; ++i)
                dma16(Wkb + w * 4096 + i * 1024 + lane * 16, Wl + 16384 + w * 4096 + i * 1024);
        } else {
            const u8* wsrc = Wvb + (size_t)r0 * 512;
            #pragma unroll
            for (int i = 0; i < 8; ++i)
                dma16(wsrc + w * 8192 + i * 1024 + lane * 16, Wl + w * 8192 + i * 1024);
        }
    }
    asm volatile("s_waitcnt vmcnt(0)" ::: "memory");
    __syncthreads();

    const int swz = li << 5;
    bf16x8 xf[8];
    #pragma unroll
    for (int ks = 0; ks < 8; ++ks)
        xf[ks] = *(const bf16x8*)(xTl + (w * 16 + li) * 512 + ((ks * 64 + 16 * g) ^ swz));

    if (split == 0) {
        f32x4 aq0 = zero, aq1 = zero, ak0 = zero, ak1 = zero;
        #pragma unroll
        for (int ks = 0; ks < 8; ++ks) {
            const int o = (ks * 64 + 16 * g) ^ swz;
            bf16x8 w0 = *(const bf16x8*)(Wl + li * 512 + o);
            bf16x8 w1 = *(const bf16x8*)(Wl + (16 + li) * 512 + o);
            bf16x8 w2 = *(const bf16x8*)(Wl + 16384 + li * 512 + o);
            bf16x8 w3 = *(const bf16x8*)(Wl + 16384 + (16 + li) * 512 + o);
            aq0 = MFMA16(w0, xf[ks], aq0);
            aq1 = MFMA16(w1, xf[ks], aq1);
            ak0 = MFMA16(w2, xf[ks], ak0);
            ak1 = MFMA16(w3, xf[ks], ak1);
        }
        const float scf = scale_p[0] * LOG2E;
        f32x4 bq0 = *(const f32x4*)(bq + 4 * g);
        f32x4 bq1 = *(const f32x4*)(bq + 16 + 4 * g);
        f32x4 bk0 = *(const f32x4*)(bk + 4 * g);
        f32x4 bk1 = *(const f32x4*)(bk + 16 + 4 * g);
        float qn2 = 0.f, kn2 = 0.f;
        ushort4 s0, s1;
        #pragma unroll
        for (int r = 0; r < 4; ++r) {
            float q0 = (aq0[r] + bq0[r]) * scf;
            float q1 = (aq1[r] + bq1[r]) * scf;
            qn2 += q0 * q0 + q1 * q1;
            ((u16*)&s0)[r] = f2b(q0); ((u16*)&s1)[r] = f2b(q1);
        }
        *(ushort4*)(qT + (size_t)(b * N_SP + n) * CQ + 4 * g)      = s0;
        *(ushort4*)(qT + (size_t)(b * N_SP + n) * CQ + 16 + 4 * g) = s1;
        #pragma unroll
        for (int r = 0; r < 4; ++r) {
            float k0 = ak0[r] + bk0[r];
            float k1 = ak1[r] + bk1[r];
            kn2 += k0 * k0 + k1 * k1;
            ((u16*)&s0)[r] = f2b(k0); ((u16*)&s1)[r] = f2b(k1);
        }
        u8* krow = Kg + ((size_t)b * N_SP + n) * 64;
        const int swn = ((n >> 1) & 3) << 4;
        *(ushort4*)(krow + ((8 * g) ^ swn))      = s0;
        *(ushort4*)(krow + ((32 + 8 * g) ^ swn)) = s1;

        qn2 += __shfl_xor(qn2, 16); qn2 += __shfl_xor(qn2, 32);
        kn2 += __shfl_xor(kn2, 16); kn2 += __shfl_xor(kn2, 32);
        if (g == 0) qnorm[b * N_SP + n] = sqrtf(qn2);
        float kn = sqrtf(kn2);
        #pragma unroll
        for (int d = 1; d < 16; d <<= 1) kn = fmaxf(kn, __shfl_xor(kn, d));
        if ((t & 63) == 0) atomicMax((int*)(kmax + b), __float_as_int(kn));
    } else {
        f32x4 a[4] = {zero, zero, zero, zero};
        #pragma unroll
        for (int ks = 0; ks < 8; ++ks) {
            const int o = (ks * 64 + 16 * g) ^ swz;
            #pragma unroll
            for (int fr = 0; fr < 4; ++fr) {
                bf16x8 wf = *(const bf16x8*)(Wl + (fr * 16 + li) * 512 + o);
                a[fr] = MFMA16(wf, xf[ks], a[fr]);
            }
        }
        // byte position for this thread's j' = w*16+li within tile nt
        const int jj = w * 16 + li;
        const int p = ((jj >> 5) & 1) * 8 + ((jj >> 3) & 3) * 16 + (jj & 7);
        u8* vtile = Vg + (size_t)(b * NJT + nt) * 16384;
        #pragma unroll
        for (int fr = 0; fr < 4; ++fr) {
            f32x4 bb = *(const f32x4*)(bv + r0 + fr * 16 + 4 * g);
            #pragma unroll
            for (int r = 0; r < 4; ++r) {
                const int c = r0 + fr * 16 + 4 * g + r;
                vtile[c * 64 + (p ^ (((c >> 1) & 3) << 4))] = f2fp8(a[fr][r] + bb[r]);
            }
        }
    }
}

// ---------------------------------------------------------------------------
// Attention (R11, verified): 196 blocks x 512 thr, ring-4 DMA depth-3,
// vmcnt(8), coalesced V/K tiles, b128 LDS reads, 2-way-max swizzles.
// ---------------------------------------------------------------------------
__global__ __launch_bounds__(512) void attn_mfma(
    const u16* __restrict__ qT, const u8* __restrict__ Kg,
    const u8* __restrict__ Vg, const float* __restrict__ x,
    const float* __restrict__ gamma_p, const float* __restrict__ qnorm,
    const float* __restrict__ kmax, float* __restrict__ out)
{
    __shared__ __align__(16) u8 smem[86016];
    u8* const Vl = smem;             // 4 x 16384
    u8* const Kl = smem + 65536;     // 4 x 4096
    u8* const Pl = smem + 81920;     // 4096 (reduce overlays here after loop)

    const int t = threadIdx.x;
    const int w = t >> 6, li = t & 15, g = (t >> 4) & 3;
    const int jh = w & 3, qh = w >> 2;
    const int cw = w * 32;
    const int swz = ((li >> 1) & 3) << 4;

    const int b  = blockIdx.x / NJT;
    const int i0 = (blockIdx.x % NJT) * QT;

    const u16* qTb = qT + (size_t)b * N_SP * CQ;
    const u8*  Kbb = Kg + (size_t)b * N_SP * 64;
    const u8*  Vbb = Vg + (size_t)b * NJT * 16384;
    const float kmb = kmax[b];
    const f32x4 zero = {0.f, 0.f, 0.f, 0.f};

    const int qA = 2 * qh, qB = 2 * qh + 1;
    const bf16x8 qfA = *(const bf16x8*)(qTb + (size_t)(i0 + qA * 16 + li) * CQ + 8 * g);
    const bf16x8 qfB = *(const bf16x8*)(qTb + (size_t)(i0 + qB * 16 + li) * CQ + 8 * g);
    const float mrA = qnorm[b * N_SP + i0 + qA * 16 + li] * kmb;
    const float mrB = qnorm[b * N_SP + i0 + qB * 16 + li] * kmb;

    f32x4 acc[4][2];
    #pragma unroll
    for (int qq = 0; qq < 4; ++qq) { acc[qq][0] = zero; acc[qq][1] = zero; }
    float lsA = 0.f, lsB = 0.f;

    #define ISSUE(jt_, s_) do {                                               \
        const u8* vsrc_ = Vbb + (size_t)(jt_) * 16384;                        \
        const u8* ksrc_ = Kbb + (size_t)(jt_) * 4096;                         \
        _Pragma("unroll")                                                     \
        for (int i_ = 0; i_ < 2; ++i_)                                        \
            dma16(vsrc_ + i_ * 8192 + t * 16,                                 \
                  Vl + (s_) * 16384 + i_ * 8192 + w * 1024);                  \
        _Pragma("unroll")                                                     \
        for (int i_ = 0; i_ < 2; ++i_)                                        \
            dma4(ksrc_ + i_ * 2048 + t * 4,                                   \
                 Kl + (s_) * 4096 + i_ * 2048 + w * 256);                     \
    } while (0)

    ISSUE(0, 0);
    ISSUE(1, 1);
    ISSUE(2, 2);

    // P write position (fixed per thread): j' = jh*16 + 4g + r
    const int p0 = ((jh >> 1) & 1) * 8 + ((jh * 2 + (g >> 1)) & 3) * 16 + 4 * (g & 1);

    for (int it = 0; it < NJT; ++it) {
        const int cur = it & 3;
        asm volatile("s_waitcnt vmcnt(8) lgkmcnt(0)" ::: "memory");
        __builtin_amdgcn_s_barrier();
        asm volatile("" ::: "memory");

        {
            int jn = it + 3; if (jn > NJT - 1) jn = NJT - 1;
            ISSUE(jn, (cur + 3) & 3);
        }

        // ---- S^T: j-frag jh x q-frags {qA, qB} ----
        const u8* Kc = Kl + cur * 4096;
        bf16x8 kf = *(const bf16x8*)(Kc + (jh * 16 + li) * 64 + ((16 * g) ^ swz));
        f32x4 sA = MFMA16(kf, qfA, zero);
        f32x4 sB = MFMA16(kf, qfB, zero);
        {
            float a0 = exp2f(sA[0] - mrA), a1 = exp2f(sA[1] - mrA);
            float a2 = exp2f(sA[2] - mrA), a3 = exp2f(sA[3] - mrA);
            lsA += (a0 + a1) + (a2 + a3);
            int pk = __builtin_amdgcn_cvt_pk_bf8_f32(a0, a1, 0, false);
            pk = __builtin_amdgcn_cvt_pk_bf8_f32(a2, a3, pk, true);
            *(u32*)(Pl + (qA * 16 + li) * 64 + (p0 ^ swz)) = (u32)pk;
            float b0 = exp2f(sB[0] - mrB), b1 = exp2f(sB[1] - mrB);
            float b2 = exp2f(sB[2] - mrB), b3 = exp2f(sB[3] - mrB);
            lsB += (b0 + b1) + (b2 + b3);
            pk = __builtin_amdgcn_cvt_pk_bf8_f32(b0, b1, 0, false);
            pk = __builtin_amdgcn_cvt_pk_bf8_f32(b2, b3, pk, true);
            *(u32*)(Pl + (qB * 16 + li) * 64 + (p0 ^ swz)) = (u32)pk;
        }
        asm volatile("s_waitcnt lgkmcnt(0)" ::: "memory");
        __builtin_amdgcn_s_barrier();
        asm volatile("" ::: "memory");

        // ---- PV: all 4 q-frags x this wave's 32 ch (b128 = both ks) ----
        const u8* Vc = Vl + cur * 16384;
        __builtin_amdgcn_s_setprio(1);
        l64x2 pa0 = *(const l64x2*)(Pl + (0 * 16 + li) * 64 + ((16 * g) ^ swz));
        l64x2 pa1 = *(const l64x2*)(Pl + (1 * 16 + li) * 64 + ((16 * g) ^ swz));
        l64x2 pa2 = *(const l64x2*)(Pl + (2 * 16 + li) * 64 + ((16 * g) ^ swz));
        l64x2 pa3 = *(const l64x2*)(Pl + (3 * 16 + li) * 64 + ((16 * g) ^ swz));
        l64x2 v0  = *(const l64x2*)(Vc + (cw + li) * 64 + ((16 * g) ^ swz));
        l64x2 v1  = *(const l64x2*)(Vc + (cw + 16 + li) * 64 + ((16 * g) ^ swz));
        acc[0][0] = MFMA8(pa0[0], v0[0], acc[0][0]);
        acc[0][1] = MFMA8(pa0[0], v1[0], acc[0][1]);
        acc[1][0] = MFMA8(pa1[0], v0[0], acc[1][0]);
        acc[1][1] = MFMA8(pa1[0], v1[0], acc[1][1]);
        acc[2][0] = MFMA8(pa2[0], v0[0], acc[2][0]);
        acc[2][1] = MFMA8(pa2[0], v1[0], acc[2][1]);
        acc[3][0] = MFMA8(pa3[0], v0[0], acc[3][0]);
        acc[3][1] = MFMA8(pa3[0], v1[0], acc[3][1]);
        acc[0][0] = MFMA8(pa0[1], v0[1], acc[0][0]);
        acc[0][1] = MFMA8(pa0[1], v1[1], acc[0][1]);
        acc[1][0] = MFMA8(pa1[1], v0[1], acc[1][0]);
        acc[1][1] = MFMA8(pa1[1], v1[1], acc[1][1]);
        acc[2][0] = MFMA8(pa2[1], v0[1], acc[2][0]);
        acc[2][1] = MFMA8(pa2[1], v1[1], acc[2][1]);
        acc[3][0] = MFMA8(pa3[1], v0[1], acc[3][0]);
        acc[3][1] = MFMA8(pa3[1], v1[1], acc[3][1]);
        __builtin_amdgcn_s_setprio(0);
    }
    #undef ISSUE

    // ---- denominators (reduce buffers overlay P region) ----
    lsA += __shfl_xor(lsA, 16); lsA += __shfl_xor(lsA, 32);
    lsB += __shfl_xor(lsB, 16); lsB += __shfl_xor(lsB, 32);
    __syncthreads();
    float* red       = (float*)Pl;
    float* red_final = (float*)(Pl + 1024);
    if ((t & 63) < 16) {
        red[w * 32 + li]      = lsA;
        red[w * 32 + 16 + li] = lsB;
    }
    __syncthreads();
    if (t < 64) {
        const int h = t >> 4, l2 = t & 15;
        float s = 0.f;
        #pragma unroll
        for (int jw = 0; jw < 4; ++jw)
            s += red[((h >> 1) * 4 + jw) * 32 + (h & 1) * 16 + l2];
        red_final[t] = s;
    }
    __syncthreads();

    // ---- epilogue ----
    const float gsc = gamma_p[0] * INV_BOUND;
    #pragma unroll
    for (int qq = 0; qq < 4; ++qq) {
        f32x4 lsv = *(const f32x4*)(red_final + qq * 16 + 4 * g);
        f32x4 rinv;
        #pragma unroll
        for (int r = 0; r < 4; ++r) rinv[r] = gsc / lsv[r];
        #pragma unroll
        for (int cf = 0; cf < 2; ++cf) {
            const int c = cw + cf * 16 + li;
            const size_t base = ((size_t)b * C_CH + c) * N_SP + i0 + qq * 16 + 4 * g;
            float4 xv = *(const float4*)(x + base);
            float4 o;
            o.x = acc[qq][cf][0] * rinv[0] + xv.x;
            o.y = acc[qq][cf][1] * rinv[1] + xv.y;
            o.z = acc[qq][cf][2] * rinv[2] + xv.z;
            o.w = acc[qq][cf][3] * rinv[3] + xv.w;
            *(float4*)(out + base) = o;
        }
    }
}

// ---------------------------------------------------------------------------
extern "C" void kernel_launch(void* const* d_in, const int* in_sizes, int n_in,
                              void* d_out, int out_size, void* d_ws, size_t ws_size,
                              hipStream_t stream)
{
    const float* x  = (const float*)d_in[0];
    const float* Wq = (const float*)d_in[1];
    const float* bq = (const float*)d_in[2];
    const float* Wk = (const float*)d_in[3];
    const float* bk = (const float*)d_in[4];
    const float* Wv = (const float*)d_in[5];
    const float* bv = (const float*)d_in[6];
    const float* gm = (const float*)d_in[7];
    float* out = (float*)d_out;
    float* ws  = (float*)d_ws;

    float* scale = ws;                       // [0..3]
    float* kmax  = ws + 4;                   // [4..7]
    float* qnorm = ws + 8;                   // NB*N_SP
    u8* Wqb = (u8*)(ws + 8 + NB * N_SP);     // 16B-aligned
    u8* Wkb = Wqb + 32 * 512;
    u8* Wvb = Wkb + 32 * 512;
    u8* xT  = Wvb + 256 * 512;
    u16* qT = (u16*)(xT + (size_t)NB * N_SP * 512);
    u8* Kg  = (u8*)(qT + (size_t)NB * N_SP * CQ);
    u8* Vg  = Kg + (size_t)NB * N_SP * 64;

    stage1_kernel<<<865, 256, 0, stream>>>(x, Wq, Wk, Wv, xT, Wqb, Wkb, Wvb, scale, kmax);
    qkv_mfma<<<980, 256, 0, stream>>>(xT, Wqb, Wkb, Wvb, bq, bk, bv, scale, qT, Kg, Vg, qnorm, kmax);
    attn_mfma<<<NB * NJT, 512, 0, stream>>>(qT, Kg, Vg, x, gm, qnorm, kmax, out);
}